// Round 6
// baseline (575.961 us; speedup 1.0000x reference)
//
#include <hip/hip_runtime.h>
#include <hip/hip_bf16.h>
#include <math.h>

#define B 32
#define S 1024
#define IN_DIM 16
#define E 128
#define NH 4
#define DH 32
#define HDIM 256
#define ROWS (B*S)   /* 32768 */
#define EPS 1e-5f

#define N_IPW (3*384*128)
#define N_SQ  (3*128*128)

typedef __bf16 bf16x8 __attribute__((ext_vector_type(8)));
typedef __bf16 bf16x4 __attribute__((ext_vector_type(4)));
typedef __bf16 bf16x2 __attribute__((ext_vector_type(2)));
typedef float f32x4 __attribute__((ext_vector_type(4)));

union BF2U { bf16x2 b; unsigned int u; };

__device__ inline unsigned int pk2(float a, float b) {
    BF2U x; x.b[0] = (__bf16)a; x.b[1] = (__bf16)b; return x.u;
}

// ---------------- weight fp32 -> bf16 conversion (one launch) ----------------
__global__ __launch_bounds__(256) void k_cvt(const float* __restrict__ ipw,
        const float* __restrict__ ow, const float* __restrict__ w1,
        const float* __restrict__ w2, __bf16* __restrict__ o)
{
    int i = blockIdx.x * 256 + threadIdx.x;
    float v;
    if (i < N_IPW) v = ipw[i];
    else if (i < N_IPW + N_SQ) v = ow[i - N_IPW];
    else if (i < N_IPW + 2 * N_SQ) v = w1[i - N_IPW - N_SQ];
    else v = w2[i - N_IPW - 2 * N_SQ];
    o[i] = (__bf16)v;
}

// ---------------- embed: h = relu(x @ Wt + b), K=16; fp32 h + bf16 twin ----------------
__global__ __launch_bounds__(128) void k_embed(const float* __restrict__ x,
        const float* __restrict__ W, const float* __restrict__ bias,
        float* __restrict__ h, __bf16* __restrict__ hb)
{
    int row0 = blockIdx.x * 8;
    int t = threadIdx.x;
    __shared__ float xs[8][16];
    xs[t >> 4][t & 15] = x[(row0 + (t >> 4)) * IN_DIM + (t & 15)];
    __syncthreads();
    float w[16];
#pragma unroll
    for (int i = 0; i < 16; ++i) w[i] = W[t * 16 + i];
    float bb = bias[t];
#pragma unroll
    for (int rr = 0; rr < 8; ++rr) {
        float acc = bb;
#pragma unroll
        for (int i = 0; i < 16; ++i) acc += xs[rr][i] * w[i];
        float v = fmaxf(acc, 0.f);
        size_t idx = (size_t)(row0 + rr) * E + t;
        h[idx] = v;
        hb[idx] = (__bf16)v;
    }
}

// ---------------- zero-LDS bf16 MFMA GEMM: C = A[M,128] @ W[N,128]^T + bias ----------------
// All fragments loaded directly from global (b128/lane, L1/L2-hot: K=128 only).
// Transposed-operand: D = W*A^T -> lane holds 4 consecutive n for one m.
// Block = 4 waves as 2x2: wave tile (MC*16) x (NC*16).
template<int NC, int MC, int RELU>
__global__ __launch_bounds__(256) void k_gemm_g(const __bf16* __restrict__ A,
        const __bf16* __restrict__ W, const float* __restrict__ bias,
        __bf16* __restrict__ C, int Ntot)
{
    int t = threadIdx.x, lane = t & 63, wv = t >> 6;
    int l15 = lane & 15, quad = lane >> 4;
    int wm = blockIdx.y * (MC * 32) + (wv & 1) * (MC * 16);
    int wn = blockIdx.x * (NC * 32) + (wv >> 1) * (NC * 16);
    f32x4 acc[NC][MC];
#pragma unroll
    for (int i = 0; i < NC; ++i)
#pragma unroll
        for (int j = 0; j < MC; ++j) acc[i][j] = (f32x4){0.f, 0.f, 0.f, 0.f};
#pragma unroll
    for (int kc = 0; kc < 4; ++kc) {
        bf16x8 aw[NC], ba[MC];
#pragma unroll
        for (int nc = 0; nc < NC; ++nc)
            aw[nc] = *(const bf16x8*)&W[(size_t)(wn + nc * 16 + l15) * 128 + kc * 32 + quad * 8];
#pragma unroll
        for (int mc = 0; mc < MC; ++mc)
            ba[mc] = *(const bf16x8*)&A[(size_t)(wm + mc * 16 + l15) * 128 + kc * 32 + quad * 8];
#pragma unroll
        for (int nc = 0; nc < NC; ++nc)
#pragma unroll
            for (int mc = 0; mc < MC; ++mc)
                acc[nc][mc] = __builtin_amdgcn_mfma_f32_16x16x32_bf16(aw[nc], ba[mc], acc[nc][mc], 0, 0, 0);
    }
#pragma unroll
    for (int nc = 0; nc < NC; ++nc) {
        float4 bv = *(const float4*)&bias[wn + nc * 16 + quad * 4];
#pragma unroll
        for (int mc = 0; mc < MC; ++mc) {
            float v0 = acc[nc][mc][0] + bv.x;
            float v1 = acc[nc][mc][1] + bv.y;
            float v2 = acc[nc][mc][2] + bv.z;
            float v3 = acc[nc][mc][3] + bv.w;
            if (RELU) {
                v0 = fmaxf(v0, 0.f); v1 = fmaxf(v1, 0.f);
                v2 = fmaxf(v2, 0.f); v3 = fmaxf(v3, 0.f);
            }
            uint2 u; u.x = pk2(v0, v1); u.y = pk2(v2, v3);
            *(uint2*)&C[(size_t)(wm + mc * 16 + l15) * Ntot + wn + nc * 16 + quad * 4] = u;
        }
    }
}

// ---------------- fused GEMM + residual + LayerNorm ----------------
// C_row = A@W^T + bias (N=128 complete per wave) -> v = C + res(h fp32)
// -> LN stats via in-lane + 2 shfl stages -> write h fp32 + hb bf16.
// Block M=64 (wave m16 x n128), grid = ROWS/64 = 512.
__global__ __launch_bounds__(256) void k_gemm_ln(const __bf16* __restrict__ A,
        const __bf16* __restrict__ W, const float* __restrict__ bias,
        const float* __restrict__ g, const float* __restrict__ bta,
        float* __restrict__ h, __bf16* __restrict__ hb)
{
    int t = threadIdx.x, lane = t & 63, wv = t >> 6;
    int l15 = lane & 15, quad = lane >> 4;
    int m = blockIdx.x * 64 + wv * 16 + l15;
    f32x4 acc[8];
#pragma unroll
    for (int i = 0; i < 8; ++i) acc[i] = (f32x4){0.f, 0.f, 0.f, 0.f};
    const __bf16* Ap = A + (size_t)m * 128 + quad * 8;
#pragma unroll
    for (int kc = 0; kc < 4; ++kc) {
        bf16x8 ba = *(const bf16x8*)&Ap[kc * 32];
#pragma unroll
        for (int nc = 0; nc < 8; ++nc) {
            bf16x8 aw = *(const bf16x8*)&W[(size_t)(nc * 16 + l15) * 128 + kc * 32 + quad * 8];
            acc[nc] = __builtin_amdgcn_mfma_f32_16x16x32_bf16(aw, ba, acc[nc], 0, 0, 0);
        }
    }
    // epilogue: v = acc + bias + res; row stats (row m: lanes l15, l15+16, +32, +48)
    float s1 = 0.f, s2 = 0.f;
#pragma unroll
    for (int nc = 0; nc < 8; ++nc) {
        float4 bv = *(const float4*)&bias[nc * 16 + quad * 4];
        float4 rv = *(const float4*)&h[(size_t)m * 128 + nc * 16 + quad * 4];
        acc[nc][0] += bv.x + rv.x; acc[nc][1] += bv.y + rv.y;
        acc[nc][2] += bv.z + rv.z; acc[nc][3] += bv.w + rv.w;
#pragma unroll
        for (int i = 0; i < 4; ++i) { s1 += acc[nc][i]; s2 += acc[nc][i] * acc[nc][i]; }
    }
    s1 += __shfl_xor(s1, 16); s1 += __shfl_xor(s1, 32);
    s2 += __shfl_xor(s2, 16); s2 += __shfl_xor(s2, 32);
    float mu = s1 * (1.f / 128.f);
    float var = s2 * (1.f / 128.f) - mu * mu;
    float rs = rsqrtf(var + EPS);
#pragma unroll
    for (int nc = 0; nc < 8; ++nc) {
        float4 gv = *(const float4*)&g[nc * 16 + quad * 4];
        float4 bb = *(const float4*)&bta[nc * 16 + quad * 4];
        float o0 = (acc[nc][0] - mu) * rs * gv.x + bb.x;
        float o1 = (acc[nc][1] - mu) * rs * gv.y + bb.y;
        float o2 = (acc[nc][2] - mu) * rs * gv.z + bb.z;
        float o3 = (acc[nc][3] - mu) * rs * gv.w + bb.w;
        float4 of; of.x = o0; of.y = o1; of.z = o2; of.w = o3;
        *(float4*)&h[(size_t)m * 128 + nc * 16 + quad * 4] = of;
        uint2 u; u.x = pk2(o0, o1); u.y = pk2(o2, o3);
        *(uint2*)&hb[(size_t)m * 128 + nc * 16 + quad * 4] = u;
    }
}

// ---------------- MFMA flash attention v2 ----------------
// K/Q fragments load DIRECTLY from global (clean b128/lane, L1/L2-hot).
// V staged via transposed gather (8 scalar b16 global loads along k ->
// one aligned ds_write_b128) into double-buffered Vt -> ONE barrier/iter.
// Pm per-wave; in-wave LDS write->read needs only compiler ordering
// (proven by R3==R4 outputs); asm clobber enforces it.
// LDS strides 88 elem (176 B: 16B-aligned rows, 2-way banks max).
__global__ __launch_bounds__(256) void k_attn2(const __bf16* __restrict__ qkv,
        __bf16* __restrict__ O)
{
    int qt = blockIdx.x & 15, bh = blockIdx.x >> 4;
    int hh = bh & 3, b = bh >> 2;
    __shared__ __attribute__((aligned(16))) __bf16 Vt[2][32][88];
    __shared__ __attribute__((aligned(16))) __bf16 Pm[4][16][88];
    int t = threadIdx.x, lane = t & 63, wv = t >> 6;
    int l15 = lane & 15, quad = lane >> 4;
    const __bf16* qb = qkv + ((size_t)(b * S) + qt * 64) * 384 + hh * 32;
    const __bf16* kb = qkv + (size_t)(b * S) * 384 + 128 + hh * 32;
    const __bf16* vb = qkv + (size_t)(b * S) * 384 + 256 + hh * 32;
    const float qscale = 0.1767766952966369f * 1.4426950408889634f;

    // Q B-frag direct from global, scale*log2e folded in
    bf16x8 bQ;
    {
        bf16x8 qv = *(const bf16x8*)&qb[(size_t)(wv * 16 + l15) * 384 + quad * 8];
#pragma unroll
        for (int j = 0; j < 8; ++j) bQ[j] = (__bf16)((float)qv[j] * qscale);
    }

    // V transposed-gather staging: thread -> (d = t&31, kblock = t>>5)
    int vd = t & 31, vkb = t >> 5;
    const __bf16* vp = vb + (size_t)(vkb * 8) * 384 + vd;
    bf16x8 vreg;
#pragma unroll
    for (int j = 0; j < 8; ++j) vreg[j] = vp[j * 384];
    *(bf16x8*)&Vt[0][vd][vkb * 8] = vreg;
#pragma unroll
    for (int j = 0; j < 8; ++j) vreg[j] = vp[(64 + j) * 384];
    __syncthreads();

    float l_acc = 0.f;
    f32x4 o0 = {0.f, 0.f, 0.f, 0.f}, o1 = {0.f, 0.f, 0.f, 0.f};

    for (int it = 0; it < 16; ++it) {
        // scores S^T: A-frag = K direct from global (row kt0+c*16+l15, col quad*8)
        const __bf16* kp = kb + (size_t)(it * 64 + l15) * 384 + quad * 8;
        f32x4 sf[4];
#pragma unroll
        for (int c = 0; c < 4; ++c) {
            bf16x8 aK = *(const bf16x8*)&kp[c * 16 * 384];
            sf[c] = __builtin_amdgcn_mfma_f32_16x16x32_bf16(aK, bQ, (f32x4){0.f, 0.f, 0.f, 0.f}, 0, 0, 0);
        }
        // softmax (no max-sub: |scores| small by construction), P[q=l15][k]
#pragma unroll
        for (int c = 0; c < 4; ++c) {
            float p0 = __builtin_amdgcn_exp2f(sf[c][0]);
            float p1 = __builtin_amdgcn_exp2f(sf[c][1]);
            float p2 = __builtin_amdgcn_exp2f(sf[c][2]);
            float p3 = __builtin_amdgcn_exp2f(sf[c][3]);
            l_acc += (p0 + p1) + (p2 + p3);
            uint2 u; u.x = pk2(p0, p1); u.y = pk2(p2, p3);
            *(uint2*)&Pm[wv][l15][c * 16 + quad * 4] = u;
        }
        __asm__ __volatile__("" ::: "memory");  // order Pm writes vs PV reads
        // PV from current V buffer
        const int cur = it & 1;
#pragma unroll
        for (int kc = 0; kc < 2; ++kc) {
            bf16x8 ap  = *(const bf16x8*)&Pm[wv][l15][kc * 32 + quad * 8];
            bf16x8 bv0 = *(const bf16x8*)&Vt[cur][l15][kc * 32 + quad * 8];
            bf16x8 bv1 = *(const bf16x8*)&Vt[cur][16 + l15][kc * 32 + quad * 8];
            o0 = __builtin_amdgcn_mfma_f32_16x16x32_bf16(ap, bv0, o0, 0, 0, 0);
            o1 = __builtin_amdgcn_mfma_f32_16x16x32_bf16(ap, bv1, o1, 0, 0, 0);
        }
        // stage next V tile into the other buffer (no conflict with readers of cur)
        if (it < 15) {
            *(bf16x8*)&Vt[cur ^ 1][vd][vkb * 8] = vreg;
            if (it < 14) {
#pragma unroll
                for (int j = 0; j < 8; ++j) vreg[j] = vp[((it + 2) * 64 + j) * 384];
            }
        }
        __syncthreads();
    }

    l_acc += __shfl_xor(l_acc, 16);
    l_acc += __shfl_xor(l_acc, 32);   // every lane: l(q=l15)
#pragma unroll
    for (int reg = 0; reg < 4; ++reg) {
        int qloc = quad * 4 + reg;
        float linv = 1.f / __shfl(l_acc, qloc);
        int row = qt * 64 + wv * 16 + qloc;
        __bf16* op = O + ((size_t)(b * S) + row) * E + hh * 32;
        op[l15] = (__bf16)(o0[reg] * linv);
        op[16 + l15] = (__bf16)(o1[reg] * linv);
    }
}

// ---------------- masked sum pool (fp32 h), 2-stage ----------------
__global__ __launch_bounds__(128) void k_pool1(const float* __restrict__ h,
        const float* __restrict__ mask, float* __restrict__ part)
{
    int bx = blockIdx.x;
    int b = bx >> 3, ch = bx & 7, t = threadIdx.x;
    float acc = 0.f;
    const float* hp = h + (size_t)(b * S + ch * 128) * E + t;
    const float* mp = mask + b * S + ch * 128;
    for (int s = 0; s < 128; ++s) acc += hp[(size_t)s * E] * mp[s];
    part[(size_t)bx * E + t] = acc;
}

__global__ __launch_bounds__(128) void k_pool2(const float* __restrict__ part,
        float* __restrict__ pooled)
{
    int b = blockIdx.x, t = threadIdx.x;
    float acc = 0.f;
#pragma unroll
    for (int c = 0; c < 8; ++c) acc += part[(size_t)(b * 8 + c) * E + t];
    pooled[b * E + t] = acc;
}

// ---------------- classifier layers (fp32, tiny) ----------------
__global__ __launch_bounds__(256) void k_cls(const float* __restrict__ in,
        const float* __restrict__ W, const float* __restrict__ bias,
        float* __restrict__ out, int K, int relu)
{
    int b = blockIdx.x, n = threadIdx.x;
    __shared__ float xs[256];
    if (n < K) xs[n] = in[b * K + n];
    __syncthreads();
    float acc = bias[n];
    for (int k = 0; k < K; ++k) acc += xs[k] * W[n * K + k];
    if (relu) acc = fmaxf(acc, 0.f);
    out[b * 256 + n] = acc;
}

__global__ __launch_bounds__(64) void k_final(const float* __restrict__ z,
        const float* __restrict__ w4, const float* __restrict__ b4,
        float* __restrict__ out)
{
    int b = blockIdx.x, t = threadIdx.x;
    float acc = 0.f;
    for (int k = t; k < 256; k += 64) acc += z[b * 256 + k] * w4[k];
#pragma unroll
    for (int o = 32; o; o >>= 1) acc += __shfl_xor(acc, o);
    if (t == 0) out[b] = 1.f / (1.f + __expf(-(acc + b4[0])));
}

extern "C" void kernel_launch(void* const* d_in, const int* in_sizes, int n_in,
                              void* d_out, int out_size, void* d_ws, size_t ws_size,
                              hipStream_t stream)
{
    const float* x     = (const float*)d_in[0];
    const float* mask  = (const float*)d_in[1];
    const float* emb_w = (const float*)d_in[2];
    const float* emb_b = (const float*)d_in[3];
    const float* ipw   = (const float*)d_in[4];
    const float* ipb   = (const float*)d_in[5];
    const float* ow    = (const float*)d_in[6];
    const float* ob    = (const float*)d_in[7];
    const float* ln1g  = (const float*)d_in[8];
    const float* ln1b  = (const float*)d_in[9];
    const float* ln2g  = (const float*)d_in[10];
    const float* ln2b  = (const float*)d_in[11];
    const float* w1    = (const float*)d_in[12];
    const float* fb1   = (const float*)d_in[13];
    const float* w2    = (const float*)d_in[14];
    const float* fb2   = (const float*)d_in[15];
    const float* cw1   = (const float*)d_in[16];
    const float* cb1   = (const float*)d_in[17];
    const float* cw2   = (const float*)d_in[18];
    const float* cb2   = (const float*)d_in[19];
    const float* cw3   = (const float*)d_in[20];
    const float* cb3   = (const float*)d_in[21];
    const float* cw4   = (const float*)d_in[22];
    const float* cb4   = (const float*)d_in[23];

    char* p = (char*)d_ws;
    float*  h    = (float*)p;    p += (size_t)ROWS * E * 4;        // 16 MB fp32 stream
    __bf16* hb   = (__bf16*)p;   p += (size_t)ROWS * E * 2;        // 8 MB bf16 twin
    __bf16* qkv  = (__bf16*)p;   p += (size_t)ROWS * 3 * E * 2;    // 24 MB
    __bf16* t0b  = (__bf16*)p;   p += (size_t)ROWS * E * 2;        // 8 MB attn out
    __bf16* t2b  = (__bf16*)p;   p += (size_t)ROWS * E * 2;        // 8 MB ffn1 out
    __bf16* wb   = (__bf16*)p;   p += (size_t)(N_IPW + 3 * N_SQ) * 2;
    float* part  = (float*)p;    p += (size_t)B * 8 * E * 4;
    float* pooled= (float*)p;    p += (size_t)B * E * 4;
    float* z1    = (float*)p;    p += (size_t)B * HDIM * 4;
    float* z2    = (float*)p;    p += (size_t)B * HDIM * 4;
    float* z3    = (float*)p;    p += (size_t)B * HDIM * 4;

    __bf16* wb_ipw = wb;
    __bf16* wb_ow  = wb + N_IPW;
    __bf16* wb_w1  = wb_ow + N_SQ;
    __bf16* wb_w2  = wb_w1 + N_SQ;

    k_cvt<<<(N_IPW + 3 * N_SQ) / 256, 256, 0, stream>>>(ipw, ow, w1, w2, wb);
    k_embed<<<ROWS / 8, 128, 0, stream>>>(x, emb_w, emb_b, h, hb);
    for (int L = 0; L < 3; ++L) {
        // QKV: N=384, block 128x96, grid (4, 256)
        k_gemm_g<3, 4, 0><<<dim3(4, ROWS / 128), 256, 0, stream>>>(
            hb, wb_ipw + (size_t)L * 384 * 128, ipb + L * 384, qkv, 384);
        k_attn2<<<B * NH * (S / 64), 256, 0, stream>>>(qkv, t0b);
        // out-proj + residual + LN1 fused
        k_gemm_ln<<<ROWS / 64, 256, 0, stream>>>(
            t0b, wb_ow + (size_t)L * 128 * 128, ob + L * 128,
            ln1g + L * E, ln1b + L * E, h, hb);
        // FFN1 (relu): N=128, block 64x64, grid (2, 512)
        k_gemm_g<2, 2, 1><<<dim3(2, ROWS / 64), 256, 0, stream>>>(
            hb, wb_w1 + (size_t)L * 128 * 128, fb1 + L * 128, t2b, 128);
        // FFN2 + residual + LN2 fused
        k_gemm_ln<<<ROWS / 64, 256, 0, stream>>>(
            t2b, wb_w2 + (size_t)L * 128 * 128, fb2 + L * 128,
            ln2g + L * E, ln2b + L * E, h, hb);
    }
    k_pool1<<<B * 8, 128, 0, stream>>>(h, mask, part);
    k_pool2<<<B, 128, 0, stream>>>(part, pooled);
    k_cls<<<B, 256, 0, stream>>>(pooled, cw1, cb1, z1, E, 1);
    k_cls<<<B, 256, 0, stream>>>(z1, cw2, cb2, z2, HDIM, 1);
    k_cls<<<B, 256, 0, stream>>>(z2, cw3, cb3, z3, HDIM, 1);
    k_final<<<B, 64, 0, stream>>>(z3, cw4, cb4, (float*)d_out);
}

// Round 7
// 386.536 us; speedup vs baseline: 1.4901x; 1.4901x over previous
//
#include <hip/hip_runtime.h>
#include <hip/hip_bf16.h>
#include <math.h>

#define B 32
#define S 1024
#define IN_DIM 16
#define E 128
#define NH 4
#define DH 32
#define HDIM 256
#define ROWS (B*S)   /* 32768 */
#define EPS 1e-5f

#define N_IPW (3*384*128)
#define N_SQ  (3*128*128)

typedef __bf16 bf16x8 __attribute__((ext_vector_type(8)));
typedef __bf16 bf16x4 __attribute__((ext_vector_type(4)));
typedef __bf16 bf16x2 __attribute__((ext_vector_type(2)));
typedef float f32x4 __attribute__((ext_vector_type(4)));

union BF2U { bf16x2 b; unsigned int u; };
__device__ inline unsigned int pk2(float a, float b) {
    BF2U x; x.b[0] = (__bf16)a; x.b[1] = (__bf16)b; return x.u;
}

// 16B logical access as two 8B LDS ops (rows padded to RP%8==4 elems are only
// 8B-aligned; RP%8==4 is what makes every hot pattern exactly 4 dwords/bank).
union U8 { bf16x8 v8; bf16x4 v4[2]; };
__device__ inline void st8(__bf16* p, bf16x8 v) {
    U8 u; u.v8 = v;
    *(bf16x4*)p = u.v4[0];
    *(bf16x4*)(p + 4) = u.v4[1];
}
__device__ inline bf16x8 ld8(const __bf16* p) {
    U8 u;
    u.v4[0] = *(const bf16x4*)p;
    u.v4[1] = *(const bf16x4*)(p + 4);
    return u.v8;
}

// ---------------- weight fp32 -> bf16 conversion ----------------
__global__ __launch_bounds__(256) void k_cvt(const float* __restrict__ ipw,
        const float* __restrict__ ow, const float* __restrict__ w1,
        const float* __restrict__ w2, __bf16* __restrict__ o)
{
    int i = blockIdx.x * 256 + threadIdx.x;
    float v;
    if (i < N_IPW) v = ipw[i];
    else if (i < N_IPW + N_SQ) v = ow[i - N_IPW];
    else if (i < N_IPW + 2 * N_SQ) v = w1[i - N_IPW - N_SQ];
    else v = w2[i - N_IPW - 2 * N_SQ];
    o[i] = (__bf16)v;
}

// ---------------- embed: h = relu(x @ Wt + b); fp32 h + bf16 twin ----------------
__global__ __launch_bounds__(128) void k_embed(const float* __restrict__ x,
        const float* __restrict__ W, const float* __restrict__ bias,
        float* __restrict__ h, __bf16* __restrict__ hb)
{
    int row0 = blockIdx.x * 8;
    int t = threadIdx.x;
    __shared__ float xs[8][16];
    xs[t >> 4][t & 15] = x[(row0 + (t >> 4)) * IN_DIM + (t & 15)];
    __syncthreads();
    float w[16];
#pragma unroll
    for (int i = 0; i < 16; ++i) w[i] = W[t * 16 + i];
    float bb = bias[t];
#pragma unroll
    for (int rr = 0; rr < 8; ++rr) {
        float acc = bb;
#pragma unroll
        for (int i = 0; i < 16; ++i) acc += xs[rr][i] * w[i];
        float v = fmaxf(acc, 0.f);
        size_t idx = (size_t)(row0 + rr) * E + t;
        h[idx] = v;
        hb[idx] = (__bf16)v;
    }
}

// ---------------- QKV GEMM (staged): qk[rows][256] + vt[b,h,d,s] ----------------
// Block 128m x 64n, grid (6, 256). Blocks n0>=256 store V transposed.
__global__ __launch_bounds__(256) void k_gemm_qkv(const __bf16* __restrict__ A,
        const __bf16* __restrict__ W, const float* __restrict__ bias,
        __bf16* __restrict__ qk, __bf16* __restrict__ vt)
{
    __shared__ __attribute__((aligned(16))) __bf16 As[128][132];
    __shared__ __attribute__((aligned(16))) __bf16 Ws[64][132];
    int t = threadIdx.x;
    int m0 = blockIdx.y * 128, n0 = blockIdx.x * 64;
    {
        int arow = t >> 1, acol = (t & 1) * 64;
        const __bf16* Ap = A + (size_t)(m0 + arow) * 128 + acol;
#pragma unroll
        for (int j = 0; j < 8; ++j)
            st8(&As[arow][acol + j * 8], *(const bf16x8*)&Ap[j * 8]);
        int wrow = t >> 2, wcol = (t & 3) * 32;
        const __bf16* Wp = W + (size_t)(n0 + wrow) * 128 + wcol;
#pragma unroll
        for (int j = 0; j < 4; ++j)
            st8(&Ws[wrow][wcol + j * 8], *(const bf16x8*)&Wp[j * 8]);
    }
    __syncthreads();
    int lane = t & 63, wv = t >> 6;
    int l15 = lane & 15, quad = lane >> 4;
    int wm = (wv & 1) * 64, wn = (wv >> 1) * 32;
    f32x4 acc[2][4];
#pragma unroll
    for (int i = 0; i < 2; ++i)
#pragma unroll
        for (int j = 0; j < 4; ++j) acc[i][j] = (f32x4){0.f, 0.f, 0.f, 0.f};
#pragma unroll
    for (int kc = 0; kc < 4; ++kc) {
        bf16x8 aw[2], ba[4];
#pragma unroll
        for (int nc = 0; nc < 2; ++nc)
            aw[nc] = ld8(&Ws[wn + nc * 16 + l15][kc * 32 + quad * 8]);
#pragma unroll
        for (int mc = 0; mc < 4; ++mc)
            ba[mc] = ld8(&As[wm + mc * 16 + l15][kc * 32 + quad * 8]);
#pragma unroll
        for (int nc = 0; nc < 2; ++nc)
#pragma unroll
            for (int mc = 0; mc < 4; ++mc)
                acc[nc][mc] = __builtin_amdgcn_mfma_f32_16x16x32_bf16(aw[nc], ba[mc], acc[nc][mc], 0, 0, 0);
    }
#pragma unroll
    for (int nc = 0; nc < 2; ++nc) {
        float4 bv = *(const float4*)&bias[n0 + wn + nc * 16 + quad * 4];
#pragma unroll
        for (int mc = 0; mc < 4; ++mc) {
            float v0 = acc[nc][mc][0] + bv.x;
            float v1 = acc[nc][mc][1] + bv.y;
            float v2 = acc[nc][mc][2] + bv.z;
            float v3 = acc[nc][mc][3] + bv.w;
            int n = n0 + wn + nc * 16 + quad * 4;
            int m = m0 + wm + mc * 16 + l15;
            if (n < 256) {
                uint2 u; u.x = pk2(v0, v1); u.y = pk2(v2, v3);
                *(uint2*)&qk[(size_t)m * 256 + n] = u;
            } else {
                int dp = n - 256;
                int hq = dp >> 5, d0 = dp & 31;
                __bf16* vp = vt + (((size_t)(m >> 10) * 4 + hq) * 32 + d0) * 1024 + (m & 1023);
                vp[0] = (__bf16)v0; vp[1024] = (__bf16)v1;
                vp[2048] = (__bf16)v2; vp[3072] = (__bf16)v3;
            }
        }
    }
}

// ---------------- FFN1 GEMM (staged, relu, bf16 C), N=128, block 128x64 ----------------
__global__ __launch_bounds__(256) void k_gemm_relu(const __bf16* __restrict__ A,
        const __bf16* __restrict__ W, const float* __restrict__ bias,
        __bf16* __restrict__ C)
{
    __shared__ __attribute__((aligned(16))) __bf16 As[128][132];
    __shared__ __attribute__((aligned(16))) __bf16 Ws[64][132];
    int t = threadIdx.x;
    int m0 = blockIdx.y * 128, n0 = blockIdx.x * 64;
    {
        int arow = t >> 1, acol = (t & 1) * 64;
        const __bf16* Ap = A + (size_t)(m0 + arow) * 128 + acol;
#pragma unroll
        for (int j = 0; j < 8; ++j)
            st8(&As[arow][acol + j * 8], *(const bf16x8*)&Ap[j * 8]);
        int wrow = t >> 2, wcol = (t & 3) * 32;
        const __bf16* Wp = W + (size_t)(n0 + wrow) * 128 + wcol;
#pragma unroll
        for (int j = 0; j < 4; ++j)
            st8(&Ws[wrow][wcol + j * 8], *(const bf16x8*)&Wp[j * 8]);
    }
    __syncthreads();
    int lane = t & 63, wv = t >> 6;
    int l15 = lane & 15, quad = lane >> 4;
    int wm = (wv & 1) * 64, wn = (wv >> 1) * 32;
    f32x4 acc[2][4];
#pragma unroll
    for (int i = 0; i < 2; ++i)
#pragma unroll
        for (int j = 0; j < 4; ++j) acc[i][j] = (f32x4){0.f, 0.f, 0.f, 0.f};
#pragma unroll
    for (int kc = 0; kc < 4; ++kc) {
        bf16x8 aw[2], ba[4];
#pragma unroll
        for (int nc = 0; nc < 2; ++nc)
            aw[nc] = ld8(&Ws[wn + nc * 16 + l15][kc * 32 + quad * 8]);
#pragma unroll
        for (int mc = 0; mc < 4; ++mc)
            ba[mc] = ld8(&As[wm + mc * 16 + l15][kc * 32 + quad * 8]);
#pragma unroll
        for (int nc = 0; nc < 2; ++nc)
#pragma unroll
            for (int mc = 0; mc < 4; ++mc)
                acc[nc][mc] = __builtin_amdgcn_mfma_f32_16x16x32_bf16(aw[nc], ba[mc], acc[nc][mc], 0, 0, 0);
    }
#pragma unroll
    for (int nc = 0; nc < 2; ++nc) {
        float4 bv = *(const float4*)&bias[n0 + wn + nc * 16 + quad * 4];
#pragma unroll
        for (int mc = 0; mc < 4; ++mc) {
            float v0 = fmaxf(acc[nc][mc][0] + bv.x, 0.f);
            float v1 = fmaxf(acc[nc][mc][1] + bv.y, 0.f);
            float v2 = fmaxf(acc[nc][mc][2] + bv.z, 0.f);
            float v3 = fmaxf(acc[nc][mc][3] + bv.w, 0.f);
            uint2 u; u.x = pk2(v0, v1); u.y = pk2(v2, v3);
            *(uint2*)&C[(size_t)(m0 + wm + mc * 16 + l15) * 128 + n0 + wn + nc * 16 + quad * 4] = u;
        }
    }
}

// ---------------- fused GEMM + residual + LayerNorm (staged) ----------------
// Block 64m x 128n (full row), 4 waves as (m-half, n-half), wave tile 32m x 64n.
// Row stats: in-wave shfl over quads + cross-wave (n-halves) LDS reduce.
__global__ __launch_bounds__(256) void k_gemm_ln(const __bf16* __restrict__ A,
        const __bf16* __restrict__ W, const float* __restrict__ bias,
        const float* __restrict__ g, const float* __restrict__ bta,
        float* __restrict__ h, __bf16* __restrict__ hb)
{
    __shared__ __attribute__((aligned(16))) __bf16 As[64][132];
    __shared__ __attribute__((aligned(16))) __bf16 Ws[128][132];
    __shared__ float red[2][64][2];
    int t = threadIdx.x;
    int m0 = blockIdx.x * 64;
    {
        int arow = t >> 2, acol = (t & 3) * 32;
        const __bf16* Ap = A + (size_t)(m0 + arow) * 128 + acol;
#pragma unroll
        for (int j = 0; j < 4; ++j)
            st8(&As[arow][acol + j * 8], *(const bf16x8*)&Ap[j * 8]);
        int wrow = t >> 1, wcol = (t & 1) * 64;
        const __bf16* Wp = W + (size_t)wrow * 128 + wcol;
#pragma unroll
        for (int j = 0; j < 8; ++j)
            st8(&Ws[wrow][wcol + j * 8], *(const bf16x8*)&Wp[j * 8]);
    }
    __syncthreads();
    int lane = t & 63, wv = t >> 6;
    int l15 = lane & 15, quad = lane >> 4;
    int nh = wv & 1, mh = wv >> 1;
    f32x4 acc[4][2];
#pragma unroll
    for (int i = 0; i < 4; ++i)
#pragma unroll
        for (int j = 0; j < 2; ++j) acc[i][j] = (f32x4){0.f, 0.f, 0.f, 0.f};
#pragma unroll
    for (int kc = 0; kc < 4; ++kc) {
        bf16x8 aw[4], ba[2];
#pragma unroll
        for (int nc = 0; nc < 4; ++nc)
            aw[nc] = ld8(&Ws[nh * 64 + nc * 16 + l15][kc * 32 + quad * 8]);
#pragma unroll
        for (int mc = 0; mc < 2; ++mc)
            ba[mc] = ld8(&As[mh * 32 + mc * 16 + l15][kc * 32 + quad * 8]);
#pragma unroll
        for (int nc = 0; nc < 4; ++nc)
#pragma unroll
            for (int mc = 0; mc < 2; ++mc)
                acc[nc][mc] = __builtin_amdgcn_mfma_f32_16x16x32_bf16(aw[nc], ba[mc], acc[nc][mc], 0, 0, 0);
    }
    // bias + residual + per-(lane,mc) partial stats
    float s1[2] = {0.f, 0.f}, s2[2] = {0.f, 0.f};
#pragma unroll
    for (int nc = 0; nc < 4; ++nc) {
        float4 bv = *(const float4*)&bias[nh * 64 + nc * 16 + quad * 4];
#pragma unroll
        for (int mc = 0; mc < 2; ++mc) {
            int m = m0 + mh * 32 + mc * 16 + l15;
            float4 rv = *(const float4*)&h[(size_t)m * 128 + nh * 64 + nc * 16 + quad * 4];
            acc[nc][mc][0] += bv.x + rv.x; acc[nc][mc][1] += bv.y + rv.y;
            acc[nc][mc][2] += bv.z + rv.z; acc[nc][mc][3] += bv.w + rv.w;
#pragma unroll
            for (int i = 0; i < 4; ++i) {
                s1[mc] += acc[nc][mc][i];
                s2[mc] += acc[nc][mc][i] * acc[nc][mc][i];
            }
        }
    }
#pragma unroll
    for (int mc = 0; mc < 2; ++mc) {
        s1[mc] += __shfl_xor(s1[mc], 16); s1[mc] += __shfl_xor(s1[mc], 32);
        s2[mc] += __shfl_xor(s2[mc], 16); s2[mc] += __shfl_xor(s2[mc], 32);
    }
    if (quad == 0) {
#pragma unroll
        for (int mc = 0; mc < 2; ++mc) {
            red[nh][mh * 32 + mc * 16 + l15][0] = s1[mc];
            red[nh][mh * 32 + mc * 16 + l15][1] = s2[mc];
        }
    }
    __syncthreads();
    float mu[2], rs[2];
#pragma unroll
    for (int mc = 0; mc < 2; ++mc) {
        int r = mh * 32 + mc * 16 + l15;
        float S1 = red[0][r][0] + red[1][r][0];
        float S2 = red[0][r][1] + red[1][r][1];
        mu[mc] = S1 * (1.f / 128.f);
        float var = S2 * (1.f / 128.f) - mu[mc] * mu[mc];
        rs[mc] = rsqrtf(var + EPS);
    }
#pragma unroll
    for (int nc = 0; nc < 4; ++nc) {
        float4 gv = *(const float4*)&g[nh * 64 + nc * 16 + quad * 4];
        float4 bb = *(const float4*)&bta[nh * 64 + nc * 16 + quad * 4];
#pragma unroll
        for (int mc = 0; mc < 2; ++mc) {
            int m = m0 + mh * 32 + mc * 16 + l15;
            float o0 = (acc[nc][mc][0] - mu[mc]) * rs[mc] * gv.x + bb.x;
            float o1 = (acc[nc][mc][1] - mu[mc]) * rs[mc] * gv.y + bb.y;
            float o2 = (acc[nc][mc][2] - mu[mc]) * rs[mc] * gv.z + bb.z;
            float o3 = (acc[nc][mc][3] - mu[mc]) * rs[mc] * gv.w + bb.w;
            float4 of; of.x = o0; of.y = o1; of.z = o2; of.w = o3;
            *(float4*)&h[(size_t)m * 128 + nh * 64 + nc * 16 + quad * 4] = of;
            uint2 u; u.x = pk2(o0, o1); u.y = pk2(o2, o3);
            *(uint2*)&hb[(size_t)m * 128 + nh * 64 + nc * 16 + quad * 4] = u;
        }
    }
}

// ---------------- MFMA flash attention v3 ----------------
// q-tile 128 (2 groups of 64), grid B*NH*8 = 1024. K from qk rows (coalesced
// b128 stage), V from pre-transposed vt (coalesced b128 stage). Double-buffered
// K/V -> 1 barrier/iter. All hot LDS patterns verified 4 dwords/bank.
__global__ __launch_bounds__(256) void k_attn3(const __bf16* __restrict__ qk,
        const __bf16* __restrict__ vt, __bf16* __restrict__ O)
{
    int qt = blockIdx.x & 7, bh = blockIdx.x >> 3;
    int hh = bh & 3, b = bh >> 2;
    __shared__ __attribute__((aligned(16))) __bf16 Kb[2][64][36];
    __shared__ __attribute__((aligned(16))) __bf16 Vb[2][32][68];
    __shared__ __attribute__((aligned(16))) __bf16 Pm[4][16][68];
    int t = threadIdx.x, lane = t & 63, wv = t >> 6;
    int l15 = lane & 15, quad = lane >> 4;
    const __bf16* qbase = qk + (size_t)(b * S) * 256 + hh * 32;
    const __bf16* kbase = qk + (size_t)(b * S) * 256 + 128 + hh * 32;
    const __bf16* vbase = vt + ((size_t)(b * 4 + hh) * 32) * 1024;
    const float qscale = 0.1767766952966369f * 1.4426950408889634f;

    bf16x8 bQ[2];
#pragma unroll
    for (int gq = 0; gq < 2; ++gq) {
        bf16x8 qv = *(const bf16x8*)&qbase[(size_t)(qt * 128 + gq * 64 + wv * 16 + l15) * 256 + quad * 8];
#pragma unroll
        for (int j = 0; j < 8; ++j) bQ[gq][j] = (__bf16)((float)qv[j] * qscale);
    }

    int ksr = t >> 2, ksc = (t & 3) * 8;   // K stage: row 0..63, 4 thr/row
    int vsr = t >> 3, vsc = (t & 7) * 8;   // V stage: row d 0..31, 8 thr/row

    {   // tile 0
        bf16x8 k0 = *(const bf16x8*)&kbase[(size_t)ksr * 256 + ksc];
        bf16x8 v0 = *(const bf16x8*)&vbase[(size_t)vsr * 1024 + vsc];
        st8(&Kb[0][ksr][ksc], k0);
        st8(&Vb[0][vsr][vsc], v0);
    }
    __syncthreads();

    float l_acc[2] = {0.f, 0.f};
    f32x4 o[2][2];
#pragma unroll
    for (int gq = 0; gq < 2; ++gq)
#pragma unroll
        for (int j = 0; j < 2; ++j) o[gq][j] = (f32x4){0.f, 0.f, 0.f, 0.f};

    for (int it = 0; it < 16; ++it) {
        const int cur = it & 1;
        bf16x8 knext, vnext;
        if (it < 15) {
            knext = *(const bf16x8*)&kbase[(size_t)((it + 1) * 64 + ksr) * 256 + ksc];
            vnext = *(const bf16x8*)&vbase[(size_t)vsr * 1024 + (it + 1) * 64 + vsc];
        }
        bf16x8 aK[4];
#pragma unroll
        for (int c = 0; c < 4; ++c)
            aK[c] = ld8(&Kb[cur][c * 16 + l15][quad * 8]);
        bf16x8 bv[2][2];
#pragma unroll
        for (int kc = 0; kc < 2; ++kc) {
            bv[kc][0] = ld8(&Vb[cur][l15][kc * 32 + quad * 8]);
            bv[kc][1] = ld8(&Vb[cur][16 + l15][kc * 32 + quad * 8]);
        }
#pragma unroll
        for (int gq = 0; gq < 2; ++gq) {
            f32x4 sf[4];
#pragma unroll
            for (int c = 0; c < 4; ++c)
                sf[c] = __builtin_amdgcn_mfma_f32_16x16x32_bf16(aK[c], bQ[gq], (f32x4){0.f, 0.f, 0.f, 0.f}, 0, 0, 0);
#pragma unroll
            for (int c = 0; c < 4; ++c) {
                float p0 = __builtin_amdgcn_exp2f(sf[c][0]);
                float p1 = __builtin_amdgcn_exp2f(sf[c][1]);
                float p2 = __builtin_amdgcn_exp2f(sf[c][2]);
                float p3 = __builtin_amdgcn_exp2f(sf[c][3]);
                l_acc[gq] += (p0 + p1) + (p2 + p3);
                uint2 u; u.x = pk2(p0, p1); u.y = pk2(p2, p3);
                *(uint2*)&Pm[wv][l15][c * 16 + quad * 4] = u;
            }
            __asm__ __volatile__("" ::: "memory");  // Pm writes before ap reads
#pragma unroll
            for (int kc = 0; kc < 2; ++kc) {
                bf16x8 ap = ld8(&Pm[wv][l15][kc * 32 + quad * 8]);
                o[gq][0] = __builtin_amdgcn_mfma_f32_16x16x32_bf16(ap, bv[kc][0], o[gq][0], 0, 0, 0);
                o[gq][1] = __builtin_amdgcn_mfma_f32_16x16x32_bf16(ap, bv[kc][1], o[gq][1], 0, 0, 0);
            }
            __asm__ __volatile__("" ::: "memory");  // ap reads before next Pm writes
        }
        if (it < 15) {
            st8(&Kb[cur ^ 1][ksr][ksc], knext);
            st8(&Vb[cur ^ 1][vsr][vsc], vnext);
            __syncthreads();
        }
    }

#pragma unroll
    for (int gq = 0; gq < 2; ++gq) {
        float la = l_acc[gq];
        la += __shfl_xor(la, 16);
        la += __shfl_xor(la, 32);
#pragma unroll
        for (int reg = 0; reg < 4; ++reg) {
            int qloc = quad * 4 + reg;
            float linv = 1.f / __shfl(la, qloc);
            int row = qt * 128 + gq * 64 + wv * 16 + qloc;
            __bf16* op = O + ((size_t)(b * S) + row) * E + hh * 32;
            op[l15] = (__bf16)(o[gq][0][reg] * linv);
            op[16 + l15] = (__bf16)(o[gq][1][reg] * linv);
        }
    }
}

// ---------------- masked sum pool stage 1 ----------------
__global__ __launch_bounds__(128) void k_pool1(const float* __restrict__ h,
        const float* __restrict__ mask, float* __restrict__ part)
{
    int bx = blockIdx.x;
    int b = bx >> 3, ch = bx & 7, t = threadIdx.x;
    float acc = 0.f;
    const float* hp = h + (size_t)(b * S + ch * 128) * E + t;
    const float* mp = mask + b * S + ch * 128;
    for (int s = 0; s < 128; ++s) acc += hp[(size_t)s * E] * mp[s];
    part[(size_t)bx * E + t] = acc;
}

// ---------------- fused head: pool2 + cls1..3 + final sigmoid ----------------
__global__ __launch_bounds__(256) void k_head(const float* __restrict__ part,
        const float* __restrict__ cw1, const float* __restrict__ cb1,
        const float* __restrict__ cw2, const float* __restrict__ cb2,
        const float* __restrict__ cw3, const float* __restrict__ cb3,
        const float* __restrict__ cw4, const float* __restrict__ cb4,
        float* __restrict__ out)
{
    int b = blockIdx.x, t = threadIdx.x;
    __shared__ float p[128], za[256], zb[256];
    __shared__ float red4[4];
    if (t < 128) {
        float a = 0.f;
#pragma unroll
        for (int c = 0; c < 8; ++c) a += part[(size_t)(b * 8 + c) * 128 + t];
        p[t] = a;
    }
    __syncthreads();
    float a1 = cb1[t];
    for (int k = 0; k < 128; ++k) a1 += p[k] * cw1[t * 128 + k];
    za[t] = fmaxf(a1, 0.f);
    __syncthreads();
    float a2 = cb2[t];
    for (int k = 0; k < 256; ++k) a2 += za[k] * cw2[t * 256 + k];
    zb[t] = fmaxf(a2, 0.f);
    __syncthreads();
    float a3 = cb3[t];
    for (int k = 0; k < 256; ++k) a3 += zb[k] * cw3[t * 256 + k];
    float z3 = fmaxf(a3, 0.f);
    float prt = z3 * cw4[t];
#pragma unroll
    for (int o2 = 32; o2; o2 >>= 1) prt += __shfl_xor(prt, o2);
    if ((t & 63) == 0) red4[t >> 6] = prt;
    __syncthreads();
    if (t == 0) {
        float sum = red4[0] + red4[1] + red4[2] + red4[3] + cb4[0];
        out[b] = 1.f / (1.f + __expf(-sum));
    }
}

extern "C" void kernel_launch(void* const* d_in, const int* in_sizes, int n_in,
                              void* d_out, int out_size, void* d_ws, size_t ws_size,
                              hipStream_t stream)
{
    const float* x     = (const float*)d_in[0];
    const float* mask  = (const float*)d_in[1];
    const float* emb_w = (const float*)d_in[2];
    const float* emb_b = (const float*)d_in[3];
    const float* ipw   = (const float*)d_in[4];
    const float* ipb   = (const float*)d_in[5];
    const float* ow    = (const float*)d_in[6];
    const float* ob    = (const float*)d_in[7];
    const float* ln1g  = (const float*)d_in[8];
    const float* ln1b  = (const float*)d_in[9];
    const float* ln2g  = (const float*)d_in[10];
    const float* ln2b  = (const float*)d_in[11];
    const float* w1    = (const float*)d_in[12];
    const float* fb1   = (const float*)d_in[13];
    const float* w2    = (const float*)d_in[14];
    const float* fb2   = (const float*)d_in[15];
    const float* cw1   = (const float*)d_in[16];
    const float* cb1   = (const float*)d_in[17];
    const float* cw2   = (const float*)d_in[18];
    const float* cb2   = (const float*)d_in[19];
    const float* cw3   = (const float*)d_in[20];
    const float* cb3   = (const float*)d_in[21];
    const float* cw4   = (const float*)d_in[22];
    const float* cb4   = (const float*)d_in[23];

    char* p = (char*)d_ws;
    float*  h    = (float*)p;    p += (size_t)ROWS * E * 4;        // 16 MB fp32 stream
    __bf16* hb   = (__bf16*)p;   p += (size_t)ROWS * E * 2;        // 8 MB bf16 twin
    __bf16* qkb  = (__bf16*)p;   p += (size_t)ROWS * 256 * 2;      // 16 MB Q|K rows
    __bf16* vtb  = (__bf16*)p;   p += (size_t)ROWS * 32 * 4 * 2 / 4; // 8 MB V^T [b,h,d,s]
    __bf16* t0b  = (__bf16*)p;   p += (size_t)ROWS * E * 2;        // 8 MB attn out
    __bf16* t2b  = (__bf16*)p;   p += (size_t)ROWS * E * 2;        // 8 MB ffn1 out
    __bf16* wb   = (__bf16*)p;   p += (size_t)(N_IPW + 3 * N_SQ) * 2;
    float* part  = (float*)p;    p += (size_t)B * 8 * E * 4;

    __bf16* wb_ipw = wb;
    __bf16* wb_ow  = wb + N_IPW;
    __bf16* wb_w1  = wb_ow + N_SQ;
    __bf16* wb_w2  = wb_w1 + N_SQ;

    k_cvt<<<(N_IPW + 3 * N_SQ) / 256, 256, 0, stream>>>(ipw, ow, w1, w2, wb);
    k_embed<<<ROWS / 8, 128, 0, stream>>>(x, emb_w, emb_b, h, hb);
    for (int L = 0; L < 3; ++L) {
        k_gemm_qkv<<<dim3(6, ROWS / 128), 256, 0, stream>>>(
            hb, wb_ipw + (size_t)L * 384 * 128, ipb + L * 384, qkb, vtb);
        k_attn3<<<B * NH * (S / 128), 256, 0, stream>>>(qkb, vtb, t0b);
        k_gemm_ln<<<ROWS / 64, 256, 0, stream>>>(
            t0b, wb_ow + (size_t)L * 128 * 128, ob + L * 128,
            ln1g + L * E, ln1b + L * E, h, hb);
        k_gemm_relu<<<dim3(2, ROWS / 128), 256, 0, stream>>>(
            hb, wb_w1 + (size_t)L * 128 * 128, fb1 + L * 128, t2b);
        k_gemm_ln<<<ROWS / 64, 256, 0, stream>>>(
            t2b, wb_w2 + (size_t)L * 128 * 128, fb2 + L * 128,
            ln2g + L * E, ln2b + L * E, h, hb);
    }
    k_pool1<<<B * 8, 128, 0, stream>>>(h, mask, part);
    k_head<<<B, 256, 0, stream>>>(part, cw1, cb1, cw2, cb2, cw3, cb3, cw4, cb4,
                                  (float*)d_out);
}

// Round 8
// 342.472 us; speedup vs baseline: 1.6818x; 1.1287x over previous
//
#include <hip/hip_runtime.h>
#include <hip/hip_bf16.h>
#include <math.h>

#define B 32
#define S 1024
#define IN_DIM 16
#define E 128
#define NH 4
#define DH 32
#define HDIM 256
#define ROWS (B*S)   /* 32768 */
#define EPS 1e-5f

#define N_IPW (3*384*128)
#define N_SQ  (3*128*128)

typedef __bf16 bf16x8 __attribute__((ext_vector_type(8)));
typedef __bf16 bf16x4 __attribute__((ext_vector_type(4)));
typedef __bf16 bf16x2 __attribute__((ext_vector_type(2)));
typedef float f32x4 __attribute__((ext_vector_type(4)));

union BF2U { bf16x2 b; unsigned int u; };
__device__ inline unsigned int pk2(float a, float b) {
    BF2U x; x.b[0] = (__bf16)a; x.b[1] = (__bf16)b; return x.u;
}

// 16B logical access as two 8B LDS ops (rows padded to RP%8==4 elems are only
// 8B-aligned; RP%8==4 makes every hot pattern exactly 4 dwords/bank).
union U8 { bf16x8 v8; bf16x4 v4[2]; };
__device__ inline void st8(__bf16* p, bf16x8 v) {
    U8 u; u.v8 = v;
    *(bf16x4*)p = u.v4[0];
    *(bf16x4*)(p + 4) = u.v4[1];
}
__device__ inline bf16x8 ld8(const __bf16* p) {
    U8 u;
    u.v4[0] = *(const bf16x4*)p;
    u.v4[1] = *(const bf16x4*)(p + 4);
    return u.v8;
}

// ---------------- weight fp32 -> bf16 conversion ----------------
__global__ __launch_bounds__(256) void k_cvt(const float* __restrict__ ipw,
        const float* __restrict__ ow, const float* __restrict__ w1,
        const float* __restrict__ w2, __bf16* __restrict__ o)
{
    int i = blockIdx.x * 256 + threadIdx.x;
    float v;
    if (i < N_IPW) v = ipw[i];
    else if (i < N_IPW + N_SQ) v = ow[i - N_IPW];
    else if (i < N_IPW + 2 * N_SQ) v = w1[i - N_IPW - N_SQ];
    else v = w2[i - N_IPW - 2 * N_SQ];
    o[i] = (__bf16)v;
}

// ---------------- embed: hb = relu(x @ Wt + b) (bf16 stream) ----------------
__global__ __launch_bounds__(128) void k_embed(const float* __restrict__ x,
        const float* __restrict__ W, const float* __restrict__ bias,
        __bf16* __restrict__ hb)
{
    int row0 = blockIdx.x * 8;
    int t = threadIdx.x;
    __shared__ float xs[8][16];
    xs[t >> 4][t & 15] = x[(row0 + (t >> 4)) * IN_DIM + (t & 15)];
    __syncthreads();
    float w[16];
#pragma unroll
    for (int i = 0; i < 16; ++i) w[i] = W[t * 16 + i];
    float bb = bias[t];
#pragma unroll
    for (int rr = 0; rr < 8; ++rr) {
        float acc = bb;
#pragma unroll
        for (int i = 0; i < 16; ++i) acc += xs[rr][i] * w[i];
        hb[(size_t)(row0 + rr) * E + t] = (__bf16)fmaxf(acc, 0.f);
    }
}

// ---------------- QKV GEMM (staged): qk[rows][256] + vt[b,h,d,s] ----------------
__global__ __launch_bounds__(256) void k_gemm_qkv(const __bf16* __restrict__ A,
        const __bf16* __restrict__ W, const float* __restrict__ bias,
        __bf16* __restrict__ qk, __bf16* __restrict__ vt)
{
    __shared__ __attribute__((aligned(16))) __bf16 As[128][132];
    __shared__ __attribute__((aligned(16))) __bf16 Ws[64][132];
    int t = threadIdx.x;
    int m0 = blockIdx.y * 128, n0 = blockIdx.x * 64;
    {
        int arow = t >> 1, acol = (t & 1) * 64;
        const __bf16* Ap = A + (size_t)(m0 + arow) * 128 + acol;
#pragma unroll
        for (int j = 0; j < 8; ++j)
            st8(&As[arow][acol + j * 8], *(const bf16x8*)&Ap[j * 8]);
        int wrow = t >> 2, wcol = (t & 3) * 32;
        const __bf16* Wp = W + (size_t)(n0 + wrow) * 128 + wcol;
#pragma unroll
        for (int j = 0; j < 4; ++j)
            st8(&Ws[wrow][wcol + j * 8], *(const bf16x8*)&Wp[j * 8]);
    }
    __syncthreads();
    int lane = t & 63, wv = t >> 6;
    int l15 = lane & 15, quad = lane >> 4;
    int wm = (wv & 1) * 64, wn = (wv >> 1) * 32;
    f32x4 acc[2][4];
#pragma unroll
    for (int i = 0; i < 2; ++i)
#pragma unroll
        for (int j = 0; j < 4; ++j) acc[i][j] = (f32x4){0.f, 0.f, 0.f, 0.f};
#pragma unroll
    for (int kc = 0; kc < 4; ++kc) {
        bf16x8 aw[2], ba[4];
#pragma unroll
        for (int nc = 0; nc < 2; ++nc)
            aw[nc] = ld8(&Ws[wn + nc * 16 + l15][kc * 32 + quad * 8]);
#pragma unroll
        for (int mc = 0; mc < 4; ++mc)
            ba[mc] = ld8(&As[wm + mc * 16 + l15][kc * 32 + quad * 8]);
#pragma unroll
        for (int nc = 0; nc < 2; ++nc)
#pragma unroll
            for (int mc = 0; mc < 4; ++mc)
                acc[nc][mc] = __builtin_amdgcn_mfma_f32_16x16x32_bf16(aw[nc], ba[mc], acc[nc][mc], 0, 0, 0);
    }
#pragma unroll
    for (int nc = 0; nc < 2; ++nc) {
        float4 bv = *(const float4*)&bias[n0 + wn + nc * 16 + quad * 4];
#pragma unroll
        for (int mc = 0; mc < 4; ++mc) {
            float v0 = acc[nc][mc][0] + bv.x;
            float v1 = acc[nc][mc][1] + bv.y;
            float v2 = acc[nc][mc][2] + bv.z;
            float v3 = acc[nc][mc][3] + bv.w;
            int n = n0 + wn + nc * 16 + quad * 4;
            int m = m0 + wm + mc * 16 + l15;
            if (n < 256) {
                uint2 u; u.x = pk2(v0, v1); u.y = pk2(v2, v3);
                *(uint2*)&qk[(size_t)m * 256 + n] = u;
            } else {
                int dp = n - 256;
                int hq = dp >> 5, d0 = dp & 31;
                __bf16* vp = vt + (((size_t)(m >> 10) * 4 + hq) * 32 + d0) * 1024 + (m & 1023);
                vp[0] = (__bf16)v0; vp[1024] = (__bf16)v1;
                vp[2048] = (__bf16)v2; vp[3072] = (__bf16)v3;
            }
        }
    }
}

// ---------------- fused GEMM + residual + LayerNorm (staged) ----------------
// Block 64m x 128n, 4 waves as (m-half, n-half). Residual from hb (bf16).
__global__ __launch_bounds__(256) void k_gemm_ln(const __bf16* __restrict__ A,
        const __bf16* __restrict__ W, const float* __restrict__ bias,
        const float* __restrict__ g, const float* __restrict__ bta,
        __bf16* __restrict__ hb)
{
    __shared__ __attribute__((aligned(16))) __bf16 As[64][132];
    __shared__ __attribute__((aligned(16))) __bf16 Ws[128][132];
    __shared__ float red[2][64][2];
    int t = threadIdx.x;
    int m0 = blockIdx.x * 64;
    {
        int arow = t >> 2, acol = (t & 3) * 32;
        const __bf16* Ap = A + (size_t)(m0 + arow) * 128 + acol;
#pragma unroll
        for (int j = 0; j < 4; ++j)
            st8(&As[arow][acol + j * 8], *(const bf16x8*)&Ap[j * 8]);
        int wrow = t >> 1, wcol = (t & 1) * 64;
        const __bf16* Wp = W + (size_t)wrow * 128 + wcol;
#pragma unroll
        for (int j = 0; j < 8; ++j)
            st8(&Ws[wrow][wcol + j * 8], *(const bf16x8*)&Wp[j * 8]);
    }
    __syncthreads();
    int lane = t & 63, wv = t >> 6;
    int l15 = lane & 15, quad = lane >> 4;
    int nh = wv & 1, mh = wv >> 1;
    f32x4 acc[4][2];
#pragma unroll
    for (int i = 0; i < 4; ++i)
#pragma unroll
        for (int j = 0; j < 2; ++j) acc[i][j] = (f32x4){0.f, 0.f, 0.f, 0.f};
#pragma unroll
    for (int kc = 0; kc < 4; ++kc) {
        bf16x8 aw[4], ba[2];
#pragma unroll
        for (int nc = 0; nc < 4; ++nc)
            aw[nc] = ld8(&Ws[nh * 64 + nc * 16 + l15][kc * 32 + quad * 8]);
#pragma unroll
        for (int mc = 0; mc < 2; ++mc)
            ba[mc] = ld8(&As[mh * 32 + mc * 16 + l15][kc * 32 + quad * 8]);
#pragma unroll
        for (int nc = 0; nc < 4; ++nc)
#pragma unroll
            for (int mc = 0; mc < 2; ++mc)
                acc[nc][mc] = __builtin_amdgcn_mfma_f32_16x16x32_bf16(aw[nc], ba[mc], acc[nc][mc], 0, 0, 0);
    }
    float s1[2] = {0.f, 0.f}, s2[2] = {0.f, 0.f};
#pragma unroll
    for (int nc = 0; nc < 4; ++nc) {
        float4 bv = *(const float4*)&bias[nh * 64 + nc * 16 + quad * 4];
#pragma unroll
        for (int mc = 0; mc < 2; ++mc) {
            int m = m0 + mh * 32 + mc * 16 + l15;
            bf16x4 rv = *(const bf16x4*)&hb[(size_t)m * 128 + nh * 64 + nc * 16 + quad * 4];
            acc[nc][mc][0] += bv.x + (float)rv[0];
            acc[nc][mc][1] += bv.y + (float)rv[1];
            acc[nc][mc][2] += bv.z + (float)rv[2];
            acc[nc][mc][3] += bv.w + (float)rv[3];
#pragma unroll
            for (int i = 0; i < 4; ++i) {
                s1[mc] += acc[nc][mc][i];
                s2[mc] += acc[nc][mc][i] * acc[nc][mc][i];
            }
        }
    }
#pragma unroll
    for (int mc = 0; mc < 2; ++mc) {
        s1[mc] += __shfl_xor(s1[mc], 16); s1[mc] += __shfl_xor(s1[mc], 32);
        s2[mc] += __shfl_xor(s2[mc], 16); s2[mc] += __shfl_xor(s2[mc], 32);
    }
    if (quad == 0) {
#pragma unroll
        for (int mc = 0; mc < 2; ++mc) {
            red[nh][mh * 32 + mc * 16 + l15][0] = s1[mc];
            red[nh][mh * 32 + mc * 16 + l15][1] = s2[mc];
        }
    }
    __syncthreads();
    float mu[2], rs[2];
#pragma unroll
    for (int mc = 0; mc < 2; ++mc) {
        int r = mh * 32 + mc * 16 + l15;
        float S1 = red[0][r][0] + red[1][r][0];
        float S2 = red[0][r][1] + red[1][r][1];
        mu[mc] = S1 * (1.f / 128.f);
        float var = S2 * (1.f / 128.f) - mu[mc] * mu[mc];
        rs[mc] = rsqrtf(var + EPS);
    }
#pragma unroll
    for (int nc = 0; nc < 4; ++nc) {
        float4 gv = *(const float4*)&g[nh * 64 + nc * 16 + quad * 4];
        float4 bb = *(const float4*)&bta[nh * 64 + nc * 16 + quad * 4];
#pragma unroll
        for (int mc = 0; mc < 2; ++mc) {
            int m = m0 + mh * 32 + mc * 16 + l15;
            float o0 = (acc[nc][mc][0] - mu[mc]) * rs[mc] * gv.x + bb.x;
            float o1 = (acc[nc][mc][1] - mu[mc]) * rs[mc] * gv.y + bb.y;
            float o2 = (acc[nc][mc][2] - mu[mc]) * rs[mc] * gv.z + bb.z;
            float o3 = (acc[nc][mc][3] - mu[mc]) * rs[mc] * gv.w + bb.w;
            uint2 u; u.x = pk2(o0, o1); u.y = pk2(o2, o3);
            *(uint2*)&hb[(size_t)m * 128 + nh * 64 + nc * 16 + quad * 4] = u;
        }
    }
}

// ---------------- fused FFN: hb = LN(hb + relu(hb@W1^T+b1)@W2^T + b2) ----------------
// Block 64m. Phase1: G1 = relu(A@W1^T+b1) (As,W1s). Phase2: residual regs from
// As, As <- G1, Ws <- W2, then G2 + residual + LN. Zero extra global traffic.
__global__ __launch_bounds__(256) void k_ffn(const __bf16* __restrict__ hbin,
        const __bf16* __restrict__ W1, const float* __restrict__ b1,
        const __bf16* __restrict__ W2, const float* __restrict__ b2,
        const float* __restrict__ g, const float* __restrict__ bta,
        __bf16* __restrict__ hb)
{
    __shared__ __attribute__((aligned(16))) __bf16 As[64][132];
    __shared__ __attribute__((aligned(16))) __bf16 Ws[128][132];
    __shared__ float red[2][64][2];
    int t = threadIdx.x;
    int m0 = blockIdx.x * 64;
    int arow = t >> 2, acol = (t & 3) * 32;
    int wrow = t >> 1, wcol = (t & 1) * 64;
    {
        const __bf16* Ap = hbin + (size_t)(m0 + arow) * 128 + acol;
#pragma unroll
        for (int j = 0; j < 4; ++j)
            st8(&As[arow][acol + j * 8], *(const bf16x8*)&Ap[j * 8]);
        const __bf16* Wp = W1 + (size_t)wrow * 128 + wcol;
#pragma unroll
        for (int j = 0; j < 8; ++j)
            st8(&Ws[wrow][wcol + j * 8], *(const bf16x8*)&Wp[j * 8]);
    }
    __syncthreads();
    int lane = t & 63, wv = t >> 6;
    int l15 = lane & 15, quad = lane >> 4;
    int nh = wv & 1, mh = wv >> 1;
    f32x4 acc[4][2];
#pragma unroll
    for (int i = 0; i < 4; ++i)
#pragma unroll
        for (int j = 0; j < 2; ++j) acc[i][j] = (f32x4){0.f, 0.f, 0.f, 0.f};
#pragma unroll
    for (int kc = 0; kc < 4; ++kc) {
        bf16x8 aw[4], ba[2];
#pragma unroll
        for (int nc = 0; nc < 4; ++nc)
            aw[nc] = ld8(&Ws[nh * 64 + nc * 16 + l15][kc * 32 + quad * 8]);
#pragma unroll
        for (int mc = 0; mc < 2; ++mc)
            ba[mc] = ld8(&As[mh * 32 + mc * 16 + l15][kc * 32 + quad * 8]);
#pragma unroll
        for (int nc = 0; nc < 4; ++nc)
#pragma unroll
            for (int mc = 0; mc < 2; ++mc)
                acc[nc][mc] = __builtin_amdgcn_mfma_f32_16x16x32_bf16(aw[nc], ba[mc], acc[nc][mc], 0, 0, 0);
    }
    __syncthreads();   // all As/Ws(W1) reads complete
    // residual regs from As (own region), then overwrite As with G1
    bf16x4 res[4][2];
#pragma unroll
    for (int nc = 0; nc < 4; ++nc)
#pragma unroll
        for (int mc = 0; mc < 2; ++mc)
            res[nc][mc] = *(const bf16x4*)&As[mh * 32 + mc * 16 + l15][nh * 64 + nc * 16 + quad * 4];
    __asm__ __volatile__("" ::: "memory");   // res reads before G1 writes
#pragma unroll
    for (int nc = 0; nc < 4; ++nc) {
        float4 bv = *(const float4*)&b1[nh * 64 + nc * 16 + quad * 4];
#pragma unroll
        for (int mc = 0; mc < 2; ++mc) {
            float v0 = fmaxf(acc[nc][mc][0] + bv.x, 0.f);
            float v1 = fmaxf(acc[nc][mc][1] + bv.y, 0.f);
            float v2 = fmaxf(acc[nc][mc][2] + bv.z, 0.f);
            float v3 = fmaxf(acc[nc][mc][3] + bv.w, 0.f);
            uint2 u; u.x = pk2(v0, v1); u.y = pk2(v2, v3);
            *(uint2*)&As[mh * 32 + mc * 16 + l15][nh * 64 + nc * 16 + quad * 4] = u;
        }
    }
    {   // stage W2
        const __bf16* Wp = W2 + (size_t)wrow * 128 + wcol;
#pragma unroll
        for (int j = 0; j < 8; ++j)
            st8(&Ws[wrow][wcol + j * 8], *(const bf16x8*)&Wp[j * 8]);
    }
    __syncthreads();   // G1 + W2 visible
#pragma unroll
    for (int i = 0; i < 4; ++i)
#pragma unroll
        for (int j = 0; j < 2; ++j) acc[i][j] = (f32x4){0.f, 0.f, 0.f, 0.f};
#pragma unroll
    for (int kc = 0; kc < 4; ++kc) {
        bf16x8 aw[4], ba[2];
#pragma unroll
        for (int nc = 0; nc < 4; ++nc)
            aw[nc] = ld8(&Ws[nh * 64 + nc * 16 + l15][kc * 32 + quad * 8]);
#pragma unroll
        for (int mc = 0; mc < 2; ++mc)
            ba[mc] = ld8(&As[mh * 32 + mc * 16 + l15][kc * 32 + quad * 8]);
#pragma unroll
        for (int nc = 0; nc < 4; ++nc)
#pragma unroll
            for (int mc = 0; mc < 2; ++mc)
                acc[nc][mc] = __builtin_amdgcn_mfma_f32_16x16x32_bf16(aw[nc], ba[mc], acc[nc][mc], 0, 0, 0);
    }
    float s1[2] = {0.f, 0.f}, s2[2] = {0.f, 0.f};
#pragma unroll
    for (int nc = 0; nc < 4; ++nc) {
        float4 bv = *(const float4*)&b2[nh * 64 + nc * 16 + quad * 4];
#pragma unroll
        for (int mc = 0; mc < 2; ++mc) {
            acc[nc][mc][0] += bv.x + (float)res[nc][mc][0];
            acc[nc][mc][1] += bv.y + (float)res[nc][mc][1];
            acc[nc][mc][2] += bv.z + (float)res[nc][mc][2];
            acc[nc][mc][3] += bv.w + (float)res[nc][mc][3];
#pragma unroll
            for (int i = 0; i < 4; ++i) {
                s1[mc] += acc[nc][mc][i];
                s2[mc] += acc[nc][mc][i] * acc[nc][mc][i];
            }
        }
    }
#pragma unroll
    for (int mc = 0; mc < 2; ++mc) {
        s1[mc] += __shfl_xor(s1[mc], 16); s1[mc] += __shfl_xor(s1[mc], 32);
        s2[mc] += __shfl_xor(s2[mc], 16); s2[mc] += __shfl_xor(s2[mc], 32);
    }
    if (quad == 0) {
#pragma unroll
        for (int mc = 0; mc < 2; ++mc) {
            red[nh][mh * 32 + mc * 16 + l15][0] = s1[mc];
            red[nh][mh * 32 + mc * 16 + l15][1] = s2[mc];
        }
    }
    __syncthreads();
    float mu[2], rs[2];
#pragma unroll
    for (int mc = 0; mc < 2; ++mc) {
        int r = mh * 32 + mc * 16 + l15;
        float S1 = red[0][r][0] + red[1][r][0];
        float S2 = red[0][r][1] + red[1][r][1];
        mu[mc] = S1 * (1.f / 128.f);
        float var = S2 * (1.f / 128.f) - mu[mc] * mu[mc];
        rs[mc] = rsqrtf(var + EPS);
    }
#pragma unroll
    for (int nc = 0; nc < 4; ++nc) {
        float4 gv = *(const float4*)&g[nh * 64 + nc * 16 + quad * 4];
        float4 bb = *(const float4*)&bta[nh * 64 + nc * 16 + quad * 4];
#pragma unroll
        for (int mc = 0; mc < 2; ++mc) {
            int m = m0 + mh * 32 + mc * 16 + l15;
            float o0 = (acc[nc][mc][0] - mu[mc]) * rs[mc] * gv.x + bb.x;
            float o1 = (acc[nc][mc][1] - mu[mc]) * rs[mc] * gv.y + bb.y;
            float o2 = (acc[nc][mc][2] - mu[mc]) * rs[mc] * gv.z + bb.z;
            float o3 = (acc[nc][mc][3] - mu[mc]) * rs[mc] * gv.w + bb.w;
            uint2 u; u.x = pk2(o0, o1); u.y = pk2(o2, o3);
            *(uint2*)&hb[(size_t)m * 128 + nh * 64 + nc * 16 + quad * 4] = u;
        }
    }
}

// ---------------- MFMA flash attention v3 (unchanged from R7) ----------------
__global__ __launch_bounds__(256) void k_attn3(const __bf16* __restrict__ qk,
        const __bf16* __restrict__ vt, __bf16* __restrict__ O)
{
    int qt = blockIdx.x & 7, bh = blockIdx.x >> 3;
    int hh = bh & 3, b = bh >> 2;
    __shared__ __attribute__((aligned(16))) __bf16 Kb[2][64][36];
    __shared__ __attribute__((aligned(16))) __bf16 Vb[2][32][68];
    __shared__ __attribute__((aligned(16))) __bf16 Pm[4][16][68];
    int t = threadIdx.x, lane = t & 63, wv = t >> 6;
    int l15 = lane & 15, quad = lane >> 4;
    const __bf16* qbase = qk + (size_t)(b * S) * 256 + hh * 32;
    const __bf16* kbase = qk + (size_t)(b * S) * 256 + 128 + hh * 32;
    const __bf16* vbase = vt + ((size_t)(b * 4 + hh) * 32) * 1024;
    const float qscale = 0.1767766952966369f * 1.4426950408889634f;

    bf16x8 bQ[2];
#pragma unroll
    for (int gq = 0; gq < 2; ++gq) {
        bf16x8 qv = *(const bf16x8*)&qbase[(size_t)(qt * 128 + gq * 64 + wv * 16 + l15) * 256 + quad * 8];
#pragma unroll
        for (int j = 0; j < 8; ++j) bQ[gq][j] = (__bf16)((float)qv[j] * qscale);
    }

    int ksr = t >> 2, ksc = (t & 3) * 8;
    int vsr = t >> 3, vsc = (t & 7) * 8;

    {
        bf16x8 k0 = *(const bf16x8*)&kbase[(size_t)ksr * 256 + ksc];
        bf16x8 v0 = *(const bf16x8*)&vbase[(size_t)vsr * 1024 + vsc];
        st8(&Kb[0][ksr][ksc], k0);
        st8(&Vb[0][vsr][vsc], v0);
    }
    __syncthreads();

    float l_acc[2] = {0.f, 0.f};
    f32x4 o[2][2];
#pragma unroll
    for (int gq = 0; gq < 2; ++gq)
#pragma unroll
        for (int j = 0; j < 2; ++j) o[gq][j] = (f32x4){0.f, 0.f, 0.f, 0.f};

    for (int it = 0; it < 16; ++it) {
        const int cur = it & 1;
        bf16x8 knext, vnext;
        if (it < 15) {
            knext = *(const bf16x8*)&kbase[(size_t)((it + 1) * 64 + ksr) * 256 + ksc];
            vnext = *(const bf16x8*)&vbase[(size_t)vsr * 1024 + (it + 1) * 64 + vsc];
        }
        bf16x8 aK[4];
#pragma unroll
        for (int c = 0; c < 4; ++c)
            aK[c] = ld8(&Kb[cur][c * 16 + l15][quad * 8]);
        bf16x8 bv[2][2];
#pragma unroll
        for (int kc = 0; kc < 2; ++kc) {
            bv[kc][0] = ld8(&Vb[cur][l15][kc * 32 + quad * 8]);
            bv[kc][1] = ld8(&Vb[cur][16 + l15][kc * 32 + quad * 8]);
        }
#pragma unroll
        for (int gq = 0; gq < 2; ++gq) {
            f32x4 sf[4];
#pragma unroll
            for (int c = 0; c < 4; ++c)
                sf[c] = __builtin_amdgcn_mfma_f32_16x16x32_bf16(aK[c], bQ[gq], (f32x4){0.f, 0.f, 0.f, 0.f}, 0, 0, 0);
#pragma unroll
            for (int c = 0; c < 4; ++c) {
                float p0 = __builtin_amdgcn_exp2f(sf[c][0]);
                float p1 = __builtin_amdgcn_exp2f(sf[c][1]);
                float p2 = __builtin_amdgcn_exp2f(sf[c][2]);
                float p3 = __builtin_amdgcn_exp2f(sf[c][3]);
                l_acc[gq] += (p0 + p1) + (p2 + p3);
                uint2 u; u.x = pk2(p0, p1); u.y = pk2(p2, p3);
                *(uint2*)&Pm[wv][l15][c * 16 + quad * 4] = u;
            }
            __asm__ __volatile__("" ::: "memory");
#pragma unroll
            for (int kc = 0; kc < 2; ++kc) {
                bf16x8 ap = ld8(&Pm[wv][l15][kc * 32 + quad * 8]);
                o[gq][0] = __builtin_amdgcn_mfma_f32_16x16x32_bf16(ap, bv[kc][0], o[gq][0], 0, 0, 0);
                o[gq][1] = __builtin_amdgcn_mfma_f32_16x16x32_bf16(ap, bv[kc][1], o[gq][1], 0, 0, 0);
            }
            __asm__ __volatile__("" ::: "memory");
        }
        if (it < 15) {
            st8(&Kb[cur ^ 1][ksr][ksc], knext);
            st8(&Vb[cur ^ 1][vsr][vsc], vnext);
            __syncthreads();
        }
    }

#pragma unroll
    for (int gq = 0; gq < 2; ++gq) {
        float la = l_acc[gq];
        la += __shfl_xor(la, 16);
        la += __shfl_xor(la, 32);
#pragma unroll
        for (int reg = 0; reg < 4; ++reg) {
            int qloc = quad * 4 + reg;
            float linv = 1.f / __shfl(la, qloc);
            int row = qt * 128 + gq * 64 + wv * 16 + qloc;
            __bf16* op = O + ((size_t)(b * S) + row) * E + hh * 32;
            op[l15] = (__bf16)(o[gq][0][reg] * linv);
            op[16 + l15] = (__bf16)(o[gq][1][reg] * linv);
        }
    }
}

// ---------------- masked sum pool stage 1 (bf16 h) ----------------
__global__ __launch_bounds__(128) void k_pool1(const __bf16* __restrict__ h,
        const float* __restrict__ mask, float* __restrict__ part)
{
    int bx = blockIdx.x;
    int b = bx >> 3, ch = bx & 7, t = threadIdx.x;
    float acc = 0.f;
    const __bf16* hp = h + (size_t)(b * S + ch * 128) * E + t;
    const float* mp = mask + b * S + ch * 128;
    for (int s = 0; s < 128; ++s) acc += (float)hp[(size_t)s * E] * mp[s];
    part[(size_t)bx * E + t] = acc;
}

// ---------------- fused head: pool2 + cls1..3 + final sigmoid ----------------
__global__ __launch_bounds__(256) void k_head(const float* __restrict__ part,
        const float* __restrict__ cw1, const float* __restrict__ cb1,
        const float* __restrict__ cw2, const float* __restrict__ cb2,
        const float* __restrict__ cw3, const float* __restrict__ cb3,
        const float* __restrict__ cw4, const float* __restrict__ cb4,
        float* __restrict__ out)
{
    int b = blockIdx.x, t = threadIdx.x;
    __shared__ float p[128], za[256], zb[256];
    __shared__ float red4[4];
    if (t < 128) {
        float a = 0.f;
#pragma unroll
        for (int c = 0; c < 8; ++c) a += part[(size_t)(b * 8 + c) * 128 + t];
        p[t] = a;
    }
    __syncthreads();
    float a1 = cb1[t];
    for (int k = 0; k < 128; ++k) a1 += p[k] * cw1[t * 128 + k];
    za[t] = fmaxf(a1, 0.f);
    __syncthreads();
    float a2 = cb2[t];
    for (int k = 0; k < 256; ++k) a2 += za[k] * cw2[t * 256 + k];
    zb[t] = fmaxf(a2, 0.f);
    __syncthreads();
    float a3 = cb3[t];
    for (int k = 0; k < 256; ++k) a3 += zb[k] * cw3[t * 256 + k];
    float z3 = fmaxf(a3, 0.f);
    float prt = z3 * cw4[t];
#pragma unroll
    for (int o2 = 32; o2; o2 >>= 1) prt += __shfl_xor(prt, o2);
    if ((t & 63) == 0) red4[t >> 6] = prt;
    __syncthreads();
    if (t == 0) {
        float sum = red4[0] + red4[1] + red4[2] + red4[3] + cb4[0];
        out[b] = 1.f / (1.f + __expf(-sum));
    }
}

extern "C" void kernel_launch(void* const* d_in, const int* in_sizes, int n_in,
                              void* d_out, int out_size, void* d_ws, size_t ws_size,
                              hipStream_t stream)
{
    const float* x     = (const float*)d_in[0];
    const float* mask  = (const float*)d_in[1];
    const float* emb_w = (const float*)d_in[2];
    const float* emb_b = (const float*)d_in[3];
    const float* ipw   = (const float*)d_in[4];
    const float* ipb   = (const float*)d_in[5];
    const float* ow    = (const float*)d_in[6];
    const float* ob    = (const float*)d_in[7];
    const float* ln1g  = (const float*)d_in[8];
    const float* ln1b  = (const float*)d_in[9];
    const float* ln2g  = (const float*)d_in[10];
    const float* ln2b  = (const float*)d_in[11];
    const float* w1    = (const float*)d_in[12];
    const float* fb1   = (const float*)d_in[13];
    const float* w2    = (const float*)d_in[14];
    const float* fb2   = (const float*)d_in[15];
    const float* cw1   = (const float*)d_in[16];
    const float* cb1   = (const float*)d_in[17];
    const float* cw2   = (const float*)d_in[18];
    const float* cb2   = (const float*)d_in[19];
    const float* cw3   = (const float*)d_in[20];
    const float* cb3   = (const float*)d_in[21];
    const float* cw4   = (const float*)d_in[22];
    const float* cb4   = (const float*)d_in[23];

    char* p = (char*)d_ws;
    __bf16* hb   = (__bf16*)p;   p += (size_t)ROWS * E * 2;        // 8 MB bf16 stream
    __bf16* qkb  = (__bf16*)p;   p += (size_t)ROWS * 256 * 2;      // 16 MB Q|K rows
    __bf16* vtb  = (__bf16*)p;   p += (size_t)ROWS * 32 * 4 * 2 / 4; // 8 MB V^T [b,h,d,s]
    __bf16* t0b  = (__bf16*)p;   p += (size_t)ROWS * E * 2;        // 8 MB attn out
    __bf16* wb   = (__bf16*)p;   p += (size_t)(N_IPW + 3 * N_SQ) * 2;
    float* part  = (float*)p;    p += (size_t)B * 8 * E * 4;

    __bf16* wb_ipw = wb;
    __bf16* wb_ow  = wb + N_IPW;
    __bf16* wb_w1  = wb_ow + N_SQ;
    __bf16* wb_w2  = wb_w1 + N_SQ;

    k_cvt<<<(N_IPW + 3 * N_SQ) / 256, 256, 0, stream>>>(ipw, ow, w1, w2, wb);
    k_embed<<<ROWS / 8, 128, 0, stream>>>(x, emb_w, emb_b, hb);
    for (int L = 0; L < 3; ++L) {
        k_gemm_qkv<<<dim3(6, ROWS / 128), 256, 0, stream>>>(
            hb, wb_ipw + (size_t)L * 384 * 128, ipb + L * 384, qkb, vtb);
        k_attn3<<<B * NH * (S / 128), 256, 0, stream>>>(qkb, vtb, t0b);
        k_gemm_ln<<<ROWS / 64, 256, 0, stream>>>(
            t0b, wb_ow + (size_t)L * 128 * 128, ob + L * 128,
            ln1g + L * E, ln1b + L * E, hb);
        k_ffn<<<ROWS / 64, 256, 0, stream>>>(
            hb, wb_w1 + (size_t)L * 128 * 128, fb1 + L * 128,
            wb_w2 + (size_t)L * 128 * 128, fb2 + L * 128,
            ln2g + L * E, ln2b + L * E, hb);
    }
    k_pool1<<<B * 8, 128, 0, stream>>>(hb, mask, part);
    k_head<<<B, 256, 0, stream>>>(part, cw1, cb1, cw2, cb2, cw3, cb3, cw4, cb4,
                                  (float*)d_out);
}

// Round 9
// 336.135 us; speedup vs baseline: 1.7135x; 1.0189x over previous
//
#include <hip/hip_runtime.h>
#include <hip/hip_bf16.h>
#include <math.h>

#define B 32
#define S 1024
#define IN_DIM 16
#define E 128
#define NH 4
#define DH 32
#define HDIM 256
#define ROWS (B*S)   /* 32768 */
#define EPS 1e-5f

#define N_IPW (3*384*128)
#define N_SQ  (3*128*128)
#define NCVT ((N_IPW + 3*N_SQ) / 256)   /* 1152 cvt blocks */

typedef __bf16 bf16x8 __attribute__((ext_vector_type(8)));
typedef __bf16 bf16x4 __attribute__((ext_vector_type(4)));
typedef __bf16 bf16x2 __attribute__((ext_vector_type(2)));
typedef float f32x4 __attribute__((ext_vector_type(4)));

union BF2U { bf16x2 b; unsigned int u; };
__device__ inline unsigned int pk2(float a, float b) {
    BF2U x; x.b[0] = (__bf16)a; x.b[1] = (__bf16)b; return x.u;
}

// 16B logical access as two 8B LDS ops (rows padded to RP%8==4 elems are only
// 8B-aligned; RP%8==4 makes every hot pattern exactly 4 dwords/bank).
union U8 { bf16x8 v8; bf16x4 v4[2]; };
__device__ inline void st8(__bf16* p, bf16x8 v) {
    U8 u; u.v8 = v;
    *(bf16x4*)p = u.v4[0];
    *(bf16x4*)(p + 4) = u.v4[1];
}
__device__ inline bf16x8 ld8(const __bf16* p) {
    U8 u;
    u.v4[0] = *(const bf16x4*)p;
    u.v4[1] = *(const bf16x4*)(p + 4);
    return u.v8;
}

// ---------------- fused weight-cvt + embed ----------------
// blocks [0, NCVT): fp32->bf16 weight conversion.
// blocks [NCVT, NCVT+2048): hb = relu(x @ Wt + b), 16 rows/block, 256 thr.
__global__ __launch_bounds__(256) void k_embedcvt(
        const float* __restrict__ ipw, const float* __restrict__ ow,
        const float* __restrict__ w1, const float* __restrict__ w2,
        __bf16* __restrict__ wbo,
        const float* __restrict__ x, const float* __restrict__ W,
        const float* __restrict__ bias, __bf16* __restrict__ hb)
{
    int t = threadIdx.x;
    if (blockIdx.x < NCVT) {
        int i = blockIdx.x * 256 + t;
        float v;
        if (i < N_IPW) v = ipw[i];
        else if (i < N_IPW + N_SQ) v = ow[i - N_IPW];
        else if (i < N_IPW + 2 * N_SQ) v = w1[i - N_IPW - N_SQ];
        else v = w2[i - N_IPW - 2 * N_SQ];
        wbo[i] = (__bf16)v;
        return;
    }
    int row0 = (blockIdx.x - NCVT) * 16;
    __shared__ float xs[16][16];
    xs[t >> 4][t & 15] = x[(row0 + (t >> 4)) * IN_DIM + (t & 15)];
    __syncthreads();
    int sub = t >> 7, tc = t & 127;
    float w[16];
#pragma unroll
    for (int i = 0; i < 16; ++i) w[i] = W[tc * 16 + i];
    float bb = bias[tc];
#pragma unroll
    for (int rr = 0; rr < 8; ++rr) {
        int lr = sub * 8 + rr;
        float acc = bb;
#pragma unroll
        for (int i = 0; i < 16; ++i) acc += xs[lr][i] * w[i];
        hb[(size_t)(row0 + lr) * E + tc] = (__bf16)fmaxf(acc, 0.f);
    }
}

// ---------------- QKV GEMM (staged): qk[rows][256] + vt[b,h,d,s] ----------------
__global__ __launch_bounds__(256) void k_gemm_qkv(const __bf16* __restrict__ A,
        const __bf16* __restrict__ W, const float* __restrict__ bias,
        __bf16* __restrict__ qk, __bf16* __restrict__ vt)
{
    __shared__ __attribute__((aligned(16))) __bf16 As[128][132];
    __shared__ __attribute__((aligned(16))) __bf16 Ws[64][132];
    int t = threadIdx.x;
    int m0 = blockIdx.y * 128, n0 = blockIdx.x * 64;
    {
        int arow = t >> 1, acol = (t & 1) * 64;
        const __bf16* Ap = A + (size_t)(m0 + arow) * 128 + acol;
#pragma unroll
        for (int j = 0; j < 8; ++j)
            st8(&As[arow][acol + j * 8], *(const bf16x8*)&Ap[j * 8]);
        int wrow = t >> 2, wcol = (t & 3) * 32;
        const __bf16* Wp = W + (size_t)(n0 + wrow) * 128 + wcol;
#pragma unroll
        for (int j = 0; j < 4; ++j)
            st8(&Ws[wrow][wcol + j * 8], *(const bf16x8*)&Wp[j * 8]);
    }
    __syncthreads();
    int lane = t & 63, wv = t >> 6;
    int l15 = lane & 15, quad = lane >> 4;
    int wm = (wv & 1) * 64, wn = (wv >> 1) * 32;
    f32x4 acc[2][4];
#pragma unroll
    for (int i = 0; i < 2; ++i)
#pragma unroll
        for (int j = 0; j < 4; ++j) acc[i][j] = (f32x4){0.f, 0.f, 0.f, 0.f};
#pragma unroll
    for (int kc = 0; kc < 4; ++kc) {
        bf16x8 aw[2], ba[4];
#pragma unroll
        for (int nc = 0; nc < 2; ++nc)
            aw[nc] = ld8(&Ws[wn + nc * 16 + l15][kc * 32 + quad * 8]);
#pragma unroll
        for (int mc = 0; mc < 4; ++mc)
            ba[mc] = ld8(&As[wm + mc * 16 + l15][kc * 32 + quad * 8]);
#pragma unroll
        for (int nc = 0; nc < 2; ++nc)
#pragma unroll
            for (int mc = 0; mc < 4; ++mc)
                acc[nc][mc] = __builtin_amdgcn_mfma_f32_16x16x32_bf16(aw[nc], ba[mc], acc[nc][mc], 0, 0, 0);
    }
#pragma unroll
    for (int nc = 0; nc < 2; ++nc) {
        float4 bv = *(const float4*)&bias[n0 + wn + nc * 16 + quad * 4];
#pragma unroll
        for (int mc = 0; mc < 4; ++mc) {
            float v0 = acc[nc][mc][0] + bv.x;
            float v1 = acc[nc][mc][1] + bv.y;
            float v2 = acc[nc][mc][2] + bv.z;
            float v3 = acc[nc][mc][3] + bv.w;
            int n = n0 + wn + nc * 16 + quad * 4;
            int m = m0 + wm + mc * 16 + l15;
            if (n < 256) {
                uint2 u; u.x = pk2(v0, v1); u.y = pk2(v2, v3);
                *(uint2*)&qk[(size_t)m * 256 + n] = u;
            } else {
                int dp = n - 256;
                int hq = dp >> 5, d0 = dp & 31;
                __bf16* vp = vt + (((size_t)(m >> 10) * 4 + hq) * 32 + d0) * 1024 + (m & 1023);
                vp[0] = (__bf16)v0; vp[1024] = (__bf16)v1;
                vp[2048] = (__bf16)v2; vp[3072] = (__bf16)v3;
            }
        }
    }
}

// ---------------- MFMA flash attention v3 (unchanged, proven) ----------------
__global__ __launch_bounds__(256) void k_attn3(const __bf16* __restrict__ qk,
        const __bf16* __restrict__ vt, __bf16* __restrict__ O)
{
    int qt = blockIdx.x & 7, bh = blockIdx.x >> 3;
    int hh = bh & 3, b = bh >> 2;
    __shared__ __attribute__((aligned(16))) __bf16 Kb[2][64][36];
    __shared__ __attribute__((aligned(16))) __bf16 Vb[2][32][68];
    __shared__ __attribute__((aligned(16))) __bf16 Pm[4][16][68];
    int t = threadIdx.x, lane = t & 63, wv = t >> 6;
    int l15 = lane & 15, quad = lane >> 4;
    const __bf16* qbase = qk + (size_t)(b * S) * 256 + hh * 32;
    const __bf16* kbase = qk + (size_t)(b * S) * 256 + 128 + hh * 32;
    const __bf16* vbase = vt + ((size_t)(b * 4 + hh) * 32) * 1024;
    const float qscale = 0.1767766952966369f * 1.4426950408889634f;

    bf16x8 bQ[2];
#pragma unroll
    for (int gq = 0; gq < 2; ++gq) {
        bf16x8 qv = *(const bf16x8*)&qbase[(size_t)(qt * 128 + gq * 64 + wv * 16 + l15) * 256 + quad * 8];
#pragma unroll
        for (int j = 0; j < 8; ++j) bQ[gq][j] = (__bf16)((float)qv[j] * qscale);
    }

    int ksr = t >> 2, ksc = (t & 3) * 8;
    int vsr = t >> 3, vsc = (t & 7) * 8;

    {
        bf16x8 k0 = *(const bf16x8*)&kbase[(size_t)ksr * 256 + ksc];
        bf16x8 v0 = *(const bf16x8*)&vbase[(size_t)vsr * 1024 + vsc];
        st8(&Kb[0][ksr][ksc], k0);
        st8(&Vb[0][vsr][vsc], v0);
    }
    __syncthreads();

    float l_acc[2] = {0.f, 0.f};
    f32x4 o[2][2];
#pragma unroll
    for (int gq = 0; gq < 2; ++gq)
#pragma unroll
        for (int j = 0; j < 2; ++j) o[gq][j] = (f32x4){0.f, 0.f, 0.f, 0.f};

    for (int it = 0; it < 16; ++it) {
        const int cur = it & 1;
        bf16x8 knext, vnext;
        if (it < 15) {
            knext = *(const bf16x8*)&kbase[(size_t)((it + 1) * 64 + ksr) * 256 + ksc];
            vnext = *(const bf16x8*)&vbase[(size_t)vsr * 1024 + (it + 1) * 64 + vsc];
        }
        bf16x8 aK[4];
#pragma unroll
        for (int c = 0; c < 4; ++c)
            aK[c] = ld8(&Kb[cur][c * 16 + l15][quad * 8]);
        bf16x8 bv[2][2];
#pragma unroll
        for (int kc = 0; kc < 2; ++kc) {
            bv[kc][0] = ld8(&Vb[cur][l15][kc * 32 + quad * 8]);
            bv[kc][1] = ld8(&Vb[cur][16 + l15][kc * 32 + quad * 8]);
        }
#pragma unroll
        for (int gq = 0; gq < 2; ++gq) {
            f32x4 sf[4];
#pragma unroll
            for (int c = 0; c < 4; ++c)
                sf[c] = __builtin_amdgcn_mfma_f32_16x16x32_bf16(aK[c], bQ[gq], (f32x4){0.f, 0.f, 0.f, 0.f}, 0, 0, 0);
#pragma unroll
            for (int c = 0; c < 4; ++c) {
                float p0 = __builtin_amdgcn_exp2f(sf[c][0]);
                float p1 = __builtin_amdgcn_exp2f(sf[c][1]);
                float p2 = __builtin_amdgcn_exp2f(sf[c][2]);
                float p3 = __builtin_amdgcn_exp2f(sf[c][3]);
                l_acc[gq] += (p0 + p1) + (p2 + p3);
                uint2 u; u.x = pk2(p0, p1); u.y = pk2(p2, p3);
                *(uint2*)&Pm[wv][l15][c * 16 + quad * 4] = u;
            }
            __asm__ __volatile__("" ::: "memory");
#pragma unroll
            for (int kc = 0; kc < 2; ++kc) {
                bf16x8 ap = ld8(&Pm[wv][l15][kc * 32 + quad * 8]);
                o[gq][0] = __builtin_amdgcn_mfma_f32_16x16x32_bf16(ap, bv[kc][0], o[gq][0], 0, 0, 0);
                o[gq][1] = __builtin_amdgcn_mfma_f32_16x16x32_bf16(ap, bv[kc][1], o[gq][1], 0, 0, 0);
            }
            __asm__ __volatile__("" ::: "memory");
        }
        if (it < 15) {
            st8(&Kb[cur ^ 1][ksr][ksc], knext);
            st8(&Vb[cur ^ 1][vsr][vsc], vnext);
            __syncthreads();
        }
    }

#pragma unroll
    for (int gq = 0; gq < 2; ++gq) {
        float la = l_acc[gq];
        la += __shfl_xor(la, 16);
        la += __shfl_xor(la, 32);
#pragma unroll
        for (int reg = 0; reg < 4; ++reg) {
            int qloc = quad * 4 + reg;
            float linv = 1.f / __shfl(la, qloc);
            int row = qt * 128 + gq * 64 + wv * 16 + qloc;
            __bf16* op = O + ((size_t)(b * S) + row) * E + hh * 32;
            op[l15] = (__bf16)(o[gq][0][reg] * linv);
            op[16 + l15] = (__bf16)(o[gq][1][reg] * linv);
        }
    }
}

// ---------------- mega-fused: out-proj + res + LN1 + FFN1 + FFN2 + res + LN2 ----------------
// Block 64m (full 128-col rows), 4 waves as (m-half, n-half). Three GEMM phases
// share As/Ws. Phase A: acc = t0b@Wo^T; +ob +hb(res1); LN1 -> xln (to As, bf16
// copy kept in regs as res2). Phase B: relu(xln@W1^T+b1) -> As. Phase C:
// As@W2^T + b2 + res2 -> LN2 -> hb. Numerics identical to R8 gemm_ln + ffn.
__global__ __launch_bounds__(256) void k_layer2(const __bf16* __restrict__ t0b,
        const __bf16* __restrict__ Wo, const float* __restrict__ ob,
        const float* __restrict__ g1, const float* __restrict__ bt1,
        const __bf16* __restrict__ W1, const float* __restrict__ b1v,
        const __bf16* __restrict__ W2, const float* __restrict__ b2v,
        const float* __restrict__ g2, const float* __restrict__ bt2,
        __bf16* __restrict__ hb)
{
    __shared__ __attribute__((aligned(16))) __bf16 As[64][132];
    __shared__ __attribute__((aligned(16))) __bf16 Ws[128][132];
    __shared__ float red[2][64][2];
    int t = threadIdx.x;
    int m0 = blockIdx.x * 64;
    int arow = t >> 2, acol = (t & 3) * 32;
    int wrow = t >> 1, wcol = (t & 1) * 64;
    {
        const __bf16* Ap = t0b + (size_t)(m0 + arow) * 128 + acol;
#pragma unroll
        for (int j = 0; j < 4; ++j)
            st8(&As[arow][acol + j * 8], *(const bf16x8*)&Ap[j * 8]);
        const __bf16* Wp = Wo + (size_t)wrow * 128 + wcol;
#pragma unroll
        for (int j = 0; j < 8; ++j)
            st8(&Ws[wrow][wcol + j * 8], *(const bf16x8*)&Wp[j * 8]);
    }
    __syncthreads();
    int lane = t & 63, wv = t >> 6;
    int l15 = lane & 15, quad = lane >> 4;
    int nh = wv & 1, mh = wv >> 1;
    f32x4 acc[4][2];

    // ---------- phase A: out-proj ----------
#pragma unroll
    for (int i = 0; i < 4; ++i)
#pragma unroll
        for (int j = 0; j < 2; ++j) acc[i][j] = (f32x4){0.f, 0.f, 0.f, 0.f};
#pragma unroll
    for (int kc = 0; kc < 4; ++kc) {
        bf16x8 aw[4], ba[2];
#pragma unroll
        for (int nc = 0; nc < 4; ++nc)
            aw[nc] = ld8(&Ws[nh * 64 + nc * 16 + l15][kc * 32 + quad * 8]);
#pragma unroll
        for (int mc = 0; mc < 2; ++mc)
            ba[mc] = ld8(&As[mh * 32 + mc * 16 + l15][kc * 32 + quad * 8]);
#pragma unroll
        for (int nc = 0; nc < 4; ++nc)
#pragma unroll
            for (int mc = 0; mc < 2; ++mc)
                acc[nc][mc] = __builtin_amdgcn_mfma_f32_16x16x32_bf16(aw[nc], ba[mc], acc[nc][mc], 0, 0, 0);
    }
    float s1[2] = {0.f, 0.f}, s2[2] = {0.f, 0.f};
#pragma unroll
    for (int nc = 0; nc < 4; ++nc) {
        float4 bv = *(const float4*)&ob[nh * 64 + nc * 16 + quad * 4];
#pragma unroll
        for (int mc = 0; mc < 2; ++mc) {
            int m = m0 + mh * 32 + mc * 16 + l15;
            bf16x4 rv = *(const bf16x4*)&hb[(size_t)m * 128 + nh * 64 + nc * 16 + quad * 4];
            acc[nc][mc][0] += bv.x + (float)rv[0];
            acc[nc][mc][1] += bv.y + (float)rv[1];
            acc[nc][mc][2] += bv.z + (float)rv[2];
            acc[nc][mc][3] += bv.w + (float)rv[3];
#pragma unroll
            for (int i = 0; i < 4; ++i) {
                s1[mc] += acc[nc][mc][i];
                s2[mc] += acc[nc][mc][i] * acc[nc][mc][i];
            }
        }
    }
#pragma unroll
    for (int mc = 0; mc < 2; ++mc) {
        s1[mc] += __shfl_xor(s1[mc], 16); s1[mc] += __shfl_xor(s1[mc], 32);
        s2[mc] += __shfl_xor(s2[mc], 16); s2[mc] += __shfl_xor(s2[mc], 32);
    }
    if (quad == 0) {
#pragma unroll
        for (int mc = 0; mc < 2; ++mc) {
            red[nh][mh * 32 + mc * 16 + l15][0] = s1[mc];
            red[nh][mh * 32 + mc * 16 + l15][1] = s2[mc];
        }
    }
    __syncthreads();   // red visible; all As/Ws(A-phase) reads complete
    float mu[2], rs[2];
#pragma unroll
    for (int mc = 0; mc < 2; ++mc) {
        int r = mh * 32 + mc * 16 + l15;
        float S1 = red[0][r][0] + red[1][r][0];
        float S2 = red[0][r][1] + red[1][r][1];
        mu[mc] = S1 * (1.f / 128.f);
        float var = S2 * (1.f / 128.f) - mu[mc] * mu[mc];
        rs[mc] = rsqrtf(var + EPS);
    }
    // LN1 -> xln: write to As (bf16) + keep res2 regs
    bf16x4 res2[4][2];
#pragma unroll
    for (int nc = 0; nc < 4; ++nc) {
        float4 gv = *(const float4*)&g1[nh * 64 + nc * 16 + quad * 4];
        float4 bb = *(const float4*)&bt1[nh * 64 + nc * 16 + quad * 4];
#pragma unroll
        for (int mc = 0; mc < 2; ++mc) {
            float o0 = (acc[nc][mc][0] - mu[mc]) * rs[mc] * gv.x + bb.x;
            float o1 = (acc[nc][mc][1] - mu[mc]) * rs[mc] * gv.y + bb.y;
            float o2 = (acc[nc][mc][2] - mu[mc]) * rs[mc] * gv.z + bb.z;
            float o3 = (acc[nc][mc][3] - mu[mc]) * rs[mc] * gv.w + bb.w;
            bf16x4 xb;
            xb[0] = (__bf16)o0; xb[1] = (__bf16)o1;
            xb[2] = (__bf16)o2; xb[3] = (__bf16)o3;
            res2[nc][mc] = xb;
            *(bf16x4*)&As[mh * 32 + mc * 16 + l15][nh * 64 + nc * 16 + quad * 4] = xb;
        }
    }
    {   // stage W1
        const __bf16* Wp = W1 + (size_t)wrow * 128 + wcol;
#pragma unroll
        for (int j = 0; j < 8; ++j)
            st8(&Ws[wrow][wcol + j * 8], *(const bf16x8*)&Wp[j * 8]);
    }
    __syncthreads();   // As=xln + Ws=W1 visible

    // ---------- phase B: FFN1 ----------
#pragma unroll
    for (int i = 0; i < 4; ++i)
#pragma unroll
        for (int j = 0; j < 2; ++j) acc[i][j] = (f32x4){0.f, 0.f, 0.f, 0.f};
#pragma unroll
    for (int kc = 0; kc < 4; ++kc) {
        bf16x8 aw[4], ba[2];
#pragma unroll
        for (int nc = 0; nc < 4; ++nc)
            aw[nc] = ld8(&Ws[nh * 64 + nc * 16 + l15][kc * 32 + quad * 8]);
#pragma unroll
        for (int mc = 0; mc < 2; ++mc)
            ba[mc] = ld8(&As[mh * 32 + mc * 16 + l15][kc * 32 + quad * 8]);
#pragma unroll
        for (int nc = 0; nc < 4; ++nc)
#pragma unroll
            for (int mc = 0; mc < 2; ++mc)
                acc[nc][mc] = __builtin_amdgcn_mfma_f32_16x16x32_bf16(aw[nc], ba[mc], acc[nc][mc], 0, 0, 0);
    }
    __syncthreads();   // all As(xln)/Ws(W1) reads complete
#pragma unroll
    for (int nc = 0; nc < 4; ++nc) {
        float4 bv = *(const float4*)&b1v[nh * 64 + nc * 16 + quad * 4];
#pragma unroll
        for (int mc = 0; mc < 2; ++mc) {
            float v0 = fmaxf(acc[nc][mc][0] + bv.x, 0.f);
            float v1 = fmaxf(acc[nc][mc][1] + bv.y, 0.f);
            float v2 = fmaxf(acc[nc][mc][2] + bv.z, 0.f);
            float v3 = fmaxf(acc[nc][mc][3] + bv.w, 0.f);
            uint2 u; u.x = pk2(v0, v1); u.y = pk2(v2, v3);
            *(uint2*)&As[mh * 32 + mc * 16 + l15][nh * 64 + nc * 16 + quad * 4] = u;
        }
    }
    {   // stage W2
        const __bf16* Wp = W2 + (size_t)wrow * 128 + wcol;
#pragma unroll
        for (int j = 0; j < 8; ++j)
            st8(&Ws[wrow][wcol + j * 8], *(const bf16x8*)&Wp[j * 8]);
    }
    __syncthreads();   // As=G1 + Ws=W2 visible

    // ---------- phase C: FFN2 + res2 + LN2 ----------
#pragma unroll
    for (int i = 0; i < 4; ++i)
#pragma unroll
        for (int j = 0; j < 2; ++j) acc[i][j] = (f32x4){0.f, 0.f, 0.f, 0.f};
#pragma unroll
    for (int kc = 0; kc < 4; ++kc) {
        bf16x8 aw[4], ba[2];
#pragma unroll
        for (int nc = 0; nc < 4; ++nc)
            aw[nc] = ld8(&Ws[nh * 64 + nc * 16 + l15][kc * 32 + quad * 8]);
#pragma unroll
        for (int mc = 0; mc < 2; ++mc)
            ba[mc] = ld8(&As[mh * 32 + mc * 16 + l15][kc * 32 + quad * 8]);
#pragma unroll
        for (int nc = 0; nc < 4; ++nc)
#pragma unroll
            for (int mc = 0; mc < 2; ++mc)
                acc[nc][mc] = __builtin_amdgcn_mfma_f32_16x16x32_bf16(aw[nc], ba[mc], acc[nc][mc], 0, 0, 0);
    }
    s1[0] = s1[1] = s2[0] = s2[1] = 0.f;
#pragma unroll
    for (int nc = 0; nc < 4; ++nc) {
        float4 bv = *(const float4*)&b2v[nh * 64 + nc * 16 + quad * 4];
#pragma unroll
        for (int mc = 0; mc < 2; ++mc) {
            acc[nc][mc][0] += bv.x + (float)res2[nc][mc][0];
            acc[nc][mc][1] += bv.y + (float)res2[nc][mc][1];
            acc[nc][mc][2] += bv.z + (float)res2[nc][mc][2];
            acc[nc][mc][3] += bv.w + (float)res2[nc][mc][3];
#pragma unroll
            for (int i = 0; i < 4; ++i) {
                s1[mc] += acc[nc][mc][i];
                s2[mc] += acc[nc][mc][i] * acc[nc][mc][i];
            }
        }
    }
#pragma unroll
    for (int mc = 0; mc < 2; ++mc) {
        s1[mc] += __shfl_xor(s1[mc], 16); s1[mc] += __shfl_xor(s1[mc], 32);
        s2[mc] += __shfl_xor(s2[mc], 16); s2[mc] += __shfl_xor(s2[mc], 32);
    }
    if (quad == 0) {
#pragma unroll
        for (int mc = 0; mc < 2; ++mc) {
            red[nh][mh * 32 + mc * 16 + l15][0] = s1[mc];
            red[nh][mh * 32 + mc * 16 + l15][1] = s2[mc];
        }
    }
    __syncthreads();
#pragma unroll
    for (int mc = 0; mc < 2; ++mc) {
        int r = mh * 32 + mc * 16 + l15;
        float S1 = red[0][r][0] + red[1][r][0];
        float S2 = red[0][r][1] + red[1][r][1];
        mu[mc] = S1 * (1.f / 128.f);
        float var = S2 * (1.f / 128.f) - mu[mc] * mu[mc];
        rs[mc] = rsqrtf(var + EPS);
    }
#pragma unroll
    for (int nc = 0; nc < 4; ++nc) {
        float4 gv = *(const float4*)&g2[nh * 64 + nc * 16 + quad * 4];
        float4 bb = *(const float4*)&bt2[nh * 64 + nc * 16 + quad * 4];
#pragma unroll
        for (int mc = 0; mc < 2; ++mc) {
            int m = m0 + mh * 32 + mc * 16 + l15;
            float o0 = (acc[nc][mc][0] - mu[mc]) * rs[mc] * gv.x + bb.x;
            float o1 = (acc[nc][mc][1] - mu[mc]) * rs[mc] * gv.y + bb.y;
            float o2 = (acc[nc][mc][2] - mu[mc]) * rs[mc] * gv.z + bb.z;
            float o3 = (acc[nc][mc][3] - mu[mc]) * rs[mc] * gv.w + bb.w;
            uint2 u; u.x = pk2(o0, o1); u.y = pk2(o2, o3);
            *(uint2*)&hb[(size_t)m * 128 + nh * 64 + nc * 16 + quad * 4] = u;
        }
    }
}

// ---------------- masked sum pool stage 1 (bf16 h) ----------------
__global__ __launch_bounds__(128) void k_pool1(const __bf16* __restrict__ h,
        const float* __restrict__ mask, float* __restrict__ part)
{
    int bx = blockIdx.x;
    int b = bx >> 3, ch = bx & 7, t = threadIdx.x;
    float acc = 0.f;
    const __bf16* hp = h + (size_t)(b * S + ch * 128) * E + t;
    const float* mp = mask + b * S + ch * 128;
    for (int s = 0; s < 128; ++s) acc += (float)hp[(size_t)s * E] * mp[s];
    part[(size_t)bx * E + t] = acc;
}

// ---------------- fused head: pool2 + cls1..3 + final sigmoid ----------------
__global__ __launch_bounds__(256) void k_head(const float* __restrict__ part,
        const float* __restrict__ cw1, const float* __restrict__ cb1,
        const float* __restrict__ cw2, const float* __restrict__ cb2,
        const float* __restrict__ cw3, const float* __restrict__ cb3,
        const float* __restrict__ cw4, const float* __restrict__ cb4,
        float* __restrict__ out)
{
    int b = blockIdx.x, t = threadIdx.x;
    __shared__ float p[128], za[256], zb[256];
    __shared__ float red4[4];
    if (t < 128) {
        float a = 0.f;
#pragma unroll
        for (int c = 0; c < 8; ++c) a += part[(size_t)(b * 8 + c) * 128 + t];
        p[t] = a;
    }
    __syncthreads();
    float a1 = cb1[t];
    for (int k = 0; k < 128; ++k) a1 += p[k] * cw1[t * 128 + k];
    za[t] = fmaxf(a1, 0.f);
    __syncthreads();
    float a2 = cb2[t];
    for (int k = 0; k < 256; ++k) a2 += za[k] * cw2[t * 256 + k];
    zb[t] = fmaxf(a2, 0.f);
    __syncthreads();
    float a3 = cb3[t];
    for (int k = 0; k < 256; ++k) a3 += zb[k] * cw3[t * 256 + k];
    float z3 = fmaxf(a3, 0.f);
    float prt = z3 * cw4[t];
#pragma unroll
    for (int o2 = 32; o2; o2 >>= 1) prt += __shfl_xor(prt, o2);
    if ((t & 63) == 0) red4[t >> 6] = prt;
    __syncthreads();
    if (t == 0) {
        float sum = red4[0] + red4[1] + red4[2] + red4[3] + cb4[0];
        out[b] = 1.f / (1.f + __expf(-sum));
    }
}

extern "C" void kernel_launch(void* const* d_in, const int* in_sizes, int n_in,
                              void* d_out, int out_size, void* d_ws, size_t ws_size,
                              hipStream_t stream)
{
    const float* x     = (const float*)d_in[0];
    const float* mask  = (const float*)d_in[1];
    const float* emb_w = (const float*)d_in[2];
    const float* emb_b = (const float*)d_in[3];
    const float* ipw   = (const float*)d_in[4];
    const float* ipb   = (const float*)d_in[5];
    const float* ow    = (const float*)d_in[6];
    const float* ob    = (const float*)d_in[7];
    const float* ln1g  = (const float*)d_in[8];
    const float* ln1b  = (const float*)d_in[9];
    const float* ln2g  = (const float*)d_in[10];
    const float* ln2b  = (const float*)d_in[11];
    const float* w1    = (const float*)d_in[12];
    const float* fb1   = (const float*)d_in[13];
    const float* w2    = (const float*)d_in[14];
    const float* fb2   = (const float*)d_in[15];
    const float* cw1   = (const float*)d_in[16];
    const float* cb1   = (const float*)d_in[17];
    const float* cw2   = (const float*)d_in[18];
    const float* cb2   = (const float*)d_in[19];
    const float* cw3   = (const float*)d_in[20];
    const float* cb3   = (const float*)d_in[21];
    const float* cw4   = (const float*)d_in[22];
    const float* cb4   = (const float*)d_in[23];

    char* p = (char*)d_ws;
    __bf16* hb   = (__bf16*)p;   p += (size_t)ROWS * E * 2;        // 8 MB bf16 stream
    __bf16* qkb  = (__bf16*)p;   p += (size_t)ROWS * 256 * 2;      // 16 MB Q|K rows
    __bf16* vtb  = (__bf16*)p;   p += (size_t)ROWS * 32 * 4 * 2 / 4; // 8 MB V^T [b,h,d,s]
    __bf16* t0b  = (__bf16*)p;   p += (size_t)ROWS * E * 2;        // 8 MB attn out
    __bf16* wb   = (__bf16*)p;   p += (size_t)(N_IPW + 3 * N_SQ) * 2;
    float* part  = (float*)p;    p += (size_t)B * 8 * E * 4;

    __bf16* wb_ipw = wb;
    __bf16* wb_ow  = wb + N_IPW;
    __bf16* wb_w1  = wb_ow + N_SQ;
    __bf16* wb_w2  = wb_w1 + N_SQ;

    k_embedcvt<<<NCVT + ROWS / 16, 256, 0, stream>>>(
        ipw, ow, w1, w2, wb, x, emb_w, emb_b, hb);
    for (int L = 0; L < 3; ++L) {
        k_gemm_qkv<<<dim3(6, ROWS / 128), 256, 0, stream>>>(
            hb, wb_ipw + (size_t)L * 384 * 128, ipb + L * 384, qkb, vtb);
        k_attn3<<<B * NH * (S / 128), 256, 0, stream>>>(qkb, vtb, t0b);
        k_layer2<<<ROWS / 64, 256, 0, stream>>>(
            t0b, wb_ow + (size_t)L * 128 * 128, ob + L * 128,
            ln1g + L * E, ln1b + L * E,
            wb_w1 + (size_t)L * 128 * 128, fb1 + L * 128,
            wb_w2 + (size_t)L * 128 * 128, fb2 + L * 128,
            ln2g + L * E, ln2b + L * E, hb);
    }
    k_pool1<<<B * 8, 128, 0, stream>>>(hb, mask, part);
    k_head<<<B, 256, 0, stream>>>(part, cw1, cb1, cw2, cb2, cw3, cb3, cw4, cb4,
                                  (float*)d_out);
}

// Round 10
// 328.251 us; speedup vs baseline: 1.7546x; 1.0240x over previous
//
#include <hip/hip_runtime.h>
#include <hip/hip_bf16.h>
#include <math.h>

#define B 32
#define S 1024
#define IN_DIM 16
#define E 128
#define NH 4
#define DH 32
#define HDIM 256
#define ROWS (B*S)   /* 32768 */
#define EPS 1e-5f

#define N_IPW (3*384*128)
#define N_SQ  (3*128*128)
#define NCVT ((N_IPW + 3*N_SQ) / 256)   /* 1152 cvt blocks */

typedef __bf16 bf16x8 __attribute__((ext_vector_type(8)));
typedef __bf16 bf16x4 __attribute__((ext_vector_type(4)));
typedef __bf16 bf16x2 __attribute__((ext_vector_type(2)));
typedef float f32x4 __attribute__((ext_vector_type(4)));

union BF2U { bf16x2 b; unsigned int u; };
__device__ inline unsigned int pk2(float a, float b) {
    BF2U x; x.b[0] = (__bf16)a; x.b[1] = (__bf16)b; return x.u;
}

// 16B logical access as two 8B LDS ops (rows padded to RP%8==4 elems are only
// 8B-aligned; RP%8==4 makes every hot pattern exactly 4 dwords/bank).
union U8 { bf16x8 v8; bf16x4 v4[2]; };
__device__ inline void st8(__bf16* p, bf16x8 v) {
    U8 u; u.v8 = v;
    *(bf16x4*)p = u.v4[0];
    *(bf16x4*)(p + 4) = u.v4[1];
}
__device__ inline bf16x8 ld8(const __bf16* p) {
    U8 u;
    u.v4[0] = *(const bf16x4*)p;
    u.v4[1] = *(const bf16x4*)(p + 4);
    return u.v8;
}

// ---------------- fused weight-cvt + embed ----------------
__global__ __launch_bounds__(256) void k_embedcvt(
        const float* __restrict__ ipw, const float* __restrict__ ow,
        const float* __restrict__ w1, const float* __restrict__ w2,
        __bf16* __restrict__ wbo,
        const float* __restrict__ x, const float* __restrict__ W,
        const float* __restrict__ bias, __bf16* __restrict__ hb)
{
    int t = threadIdx.x;
    if (blockIdx.x < NCVT) {
        int i = blockIdx.x * 256 + t;
        float v;
        if (i < N_IPW) v = ipw[i];
        else if (i < N_IPW + N_SQ) v = ow[i - N_IPW];
        else if (i < N_IPW + 2 * N_SQ) v = w1[i - N_IPW - N_SQ];
        else v = w2[i - N_IPW - 2 * N_SQ];
        wbo[i] = (__bf16)v;
        return;
    }
    int row0 = (blockIdx.x - NCVT) * 16;
    __shared__ float xs[16][16];
    xs[t >> 4][t & 15] = x[(row0 + (t >> 4)) * IN_DIM + (t & 15)];
    __syncthreads();
    int sub = t >> 7, tc = t & 127;
    float w[16];
#pragma unroll
    for (int i = 0; i < 16; ++i) w[i] = W[tc * 16 + i];
    float bb = bias[tc];
#pragma unroll
    for (int rr = 0; rr < 8; ++rr) {
        int lr = sub * 8 + rr;
        float acc = bb;
#pragma unroll
        for (int i = 0; i < 16; ++i) acc += xs[lr][i] * w[i];
        hb[(size_t)(row0 + lr) * E + tc] = (__bf16)fmaxf(acc, 0.f);
    }
}

// ---------------- QKV GEMM (staged): qk[rows][256] + vt[b,h,d,s] ----------------
__global__ __launch_bounds__(256) void k_gemm_qkv(const __bf16* __restrict__ A,
        const __bf16* __restrict__ W, const float* __restrict__ bias,
        __bf16* __restrict__ qk, __bf16* __restrict__ vt)
{
    __shared__ __attribute__((aligned(16))) __bf16 As[128][132];
    __shared__ __attribute__((aligned(16))) __bf16 Ws[64][132];
    int t = threadIdx.x;
    int m0 = blockIdx.y * 128, n0 = blockIdx.x * 64;
    {
        int arow = t >> 1, acol = (t & 1) * 64;
        const __bf16* Ap = A + (size_t)(m0 + arow) * 128 + acol;
#pragma unroll
        for (int j = 0; j < 8; ++j)
            st8(&As[arow][acol + j * 8], *(const bf16x8*)&Ap[j * 8]);
        int wrow = t >> 2, wcol = (t & 3) * 32;
        const __bf16* Wp = W + (size_t)(n0 + wrow) * 128 + wcol;
#pragma unroll
        for (int j = 0; j < 4; ++j)
            st8(&Ws[wrow][wcol + j * 8], *(const bf16x8*)&Wp[j * 8]);
    }
    __syncthreads();
    int lane = t & 63, wv = t >> 6;
    int l15 = lane & 15, quad = lane >> 4;
    int wm = (wv & 1) * 64, wn = (wv >> 1) * 32;
    f32x4 acc[2][4];
#pragma unroll
    for (int i = 0; i < 2; ++i)
#pragma unroll
        for (int j = 0; j < 4; ++j) acc[i][j] = (f32x4){0.f, 0.f, 0.f, 0.f};
#pragma unroll
    for (int kc = 0; kc < 4; ++kc) {
        bf16x8 aw[2], ba[4];
#pragma unroll
        for (int nc = 0; nc < 2; ++nc)
            aw[nc] = ld8(&Ws[wn + nc * 16 + l15][kc * 32 + quad * 8]);
#pragma unroll
        for (int mc = 0; mc < 4; ++mc)
            ba[mc] = ld8(&As[wm + mc * 16 + l15][kc * 32 + quad * 8]);
#pragma unroll
        for (int nc = 0; nc < 2; ++nc)
#pragma unroll
            for (int mc = 0; mc < 4; ++mc)
                acc[nc][mc] = __builtin_amdgcn_mfma_f32_16x16x32_bf16(aw[nc], ba[mc], acc[nc][mc], 0, 0, 0);
    }
#pragma unroll
    for (int nc = 0; nc < 2; ++nc) {
        float4 bv = *(const float4*)&bias[n0 + wn + nc * 16 + quad * 4];
#pragma unroll
        for (int mc = 0; mc < 4; ++mc) {
            float v0 = acc[nc][mc][0] + bv.x;
            float v1 = acc[nc][mc][1] + bv.y;
            float v2 = acc[nc][mc][2] + bv.z;
            float v3 = acc[nc][mc][3] + bv.w;
            int n = n0 + wn + nc * 16 + quad * 4;
            int m = m0 + wm + mc * 16 + l15;
            if (n < 256) {
                uint2 u; u.x = pk2(v0, v1); u.y = pk2(v2, v3);
                *(uint2*)&qk[(size_t)m * 256 + n] = u;
            } else {
                int dp = n - 256;
                int hq = dp >> 5, d0 = dp & 31;
                __bf16* vp = vt + (((size_t)(m >> 10) * 4 + hq) * 32 + d0) * 1024 + (m & 1023);
                vp[0] = (__bf16)v0; vp[1024] = (__bf16)v1;
                vp[2048] = (__bf16)v2; vp[3072] = (__bf16)v3;
            }
        }
    }
}

// ---------------- MFMA flash attention v4 ----------------
// Changes vs v3 (R9): (1) Schraudolph exp2 — 2^23 folded into Q scale, the
// score MFMA's C-input pre-biased with (127<<23 - 0.03*2^23); p = float bits
// of int(sf), bf16(p) = i>>16 via v_perm. Softmax VALU per c: 4 cvt + 2 perm
// (was 4 v_exp + 4 add + 2 cvt_pk). (2) row-sum l via ones-MFMA on the idle
// MFMA pipe (drops all adds + the epilogue shuffles; linv lands in o's
// C-layout row). (3) per-gq Pm buffers -> gq0/gq1 chains independent,
// 2 asm barriers/iter instead of 4.
__global__ __launch_bounds__(256) void k_attn4(const __bf16* __restrict__ qk,
        const __bf16* __restrict__ vt, __bf16* __restrict__ O)
{
    int qt = blockIdx.x & 7, bh = blockIdx.x >> 3;
    int hh = bh & 3, b = bh >> 2;
    __shared__ __attribute__((aligned(16))) __bf16 Kb[2][64][36];
    __shared__ __attribute__((aligned(16))) __bf16 Vb[2][32][68];
    __shared__ __attribute__((aligned(16))) __bf16 Pm[2][4][16][68];
    int t = threadIdx.x, lane = t & 63, wv = t >> 6;
    int l15 = lane & 15, quad = lane >> 4;
    const __bf16* qbase = qk + (size_t)(b * S) * 256 + hh * 32;
    const __bf16* kbase = qk + (size_t)(b * S) * 256 + 128 + hh * 32;
    const __bf16* vbase = vt + ((size_t)(b * 4 + hh) * 32) * 1024;
    // scale * log2(e) * 2^23 (Schraudolph pre-scale)
    const float qscale = 0.1767766952966369f * 1.4426950408889634f * 8388608.0f;
    const float C2 = 1065101558.0f;   // (127<<23) - 0.03*2^23
    const f32x4 cinit = {C2, C2, C2, C2};
    bf16x8 vones;
#pragma unroll
    for (int j = 0; j < 8; ++j) vones[j] = (__bf16)1.0f;

    bf16x8 bQ[2];
#pragma unroll
    for (int gq = 0; gq < 2; ++gq) {
        bf16x8 qv = *(const bf16x8*)&qbase[(size_t)(qt * 128 + gq * 64 + wv * 16 + l15) * 256 + quad * 8];
#pragma unroll
        for (int j = 0; j < 8; ++j) bQ[gq][j] = (__bf16)((float)qv[j] * qscale);
    }

    int ksr = t >> 2, ksc = (t & 3) * 8;
    int vsr = t >> 3, vsc = (t & 7) * 8;

    {
        bf16x8 k0 = *(const bf16x8*)&kbase[(size_t)ksr * 256 + ksc];
        bf16x8 v0 = *(const bf16x8*)&vbase[(size_t)vsr * 1024 + vsc];
        st8(&Kb[0][ksr][ksc], k0);
        st8(&Vb[0][vsr][vsc], v0);
    }
    __syncthreads();

    f32x4 o[2][2], ol[2];
#pragma unroll
    for (int gq = 0; gq < 2; ++gq) {
        ol[gq] = (f32x4){0.f, 0.f, 0.f, 0.f};
#pragma unroll
        for (int j = 0; j < 2; ++j) o[gq][j] = (f32x4){0.f, 0.f, 0.f, 0.f};
    }

    for (int it = 0; it < 16; ++it) {
        const int cur = it & 1;
        bf16x8 knext, vnext;
        if (it < 15) {
            knext = *(const bf16x8*)&kbase[(size_t)((it + 1) * 64 + ksr) * 256 + ksc];
            vnext = *(const bf16x8*)&vbase[(size_t)vsr * 1024 + (it + 1) * 64 + vsc];
        }
        bf16x8 aK[4];
#pragma unroll
        for (int c = 0; c < 4; ++c)
            aK[c] = ld8(&Kb[cur][c * 16 + l15][quad * 8]);
        bf16x8 bv[2][2];
#pragma unroll
        for (int kc = 0; kc < 2; ++kc) {
            bv[kc][0] = ld8(&Vb[cur][l15][kc * 32 + quad * 8]);
            bv[kc][1] = ld8(&Vb[cur][16 + l15][kc * 32 + quad * 8]);
        }
        // phase 1: scores + approx-exp + pack, both gq independent
#pragma unroll
        for (int gq = 0; gq < 2; ++gq) {
            f32x4 sf[4];
#pragma unroll
            for (int c = 0; c < 4; ++c)
                sf[c] = __builtin_amdgcn_mfma_f32_16x16x32_bf16(aK[c], bQ[gq], cinit, 0, 0, 0);
#pragma unroll
            for (int c = 0; c < 4; ++c) {
                int i0 = (int)sf[c][0];
                int i1 = (int)sf[c][1];
                int i2 = (int)sf[c][2];
                int i3 = (int)sf[c][3];
                uint2 u;
                u.x = __builtin_amdgcn_perm((unsigned)i1, (unsigned)i0, 0x07060302u);
                u.y = __builtin_amdgcn_perm((unsigned)i3, (unsigned)i2, 0x07060302u);
                *(uint2*)&Pm[gq][wv][l15][c * 16 + quad * 4] = u;
            }
        }
        __asm__ __volatile__("" ::: "memory");  // Pm writes before ap reads
        // phase 2: PV + l via ones-MFMA
#pragma unroll
        for (int gq = 0; gq < 2; ++gq) {
#pragma unroll
            for (int kc = 0; kc < 2; ++kc) {
                bf16x8 ap = ld8(&Pm[gq][wv][l15][kc * 32 + quad * 8]);
                o[gq][0] = __builtin_amdgcn_mfma_f32_16x16x32_bf16(ap, bv[kc][0], o[gq][0], 0, 0, 0);
                o[gq][1] = __builtin_amdgcn_mfma_f32_16x16x32_bf16(ap, bv[kc][1], o[gq][1], 0, 0, 0);
                ol[gq]   = __builtin_amdgcn_mfma_f32_16x16x32_bf16(ap, vones, ol[gq], 0, 0, 0);
            }
        }
        __asm__ __volatile__("" ::: "memory");  // ap reads before next Pm writes
        if (it < 15) {
            st8(&Kb[cur ^ 1][ksr][ksc], knext);
            st8(&Vb[cur ^ 1][vsr][vsc], vnext);
            __syncthreads();
        }
    }

#pragma unroll
    for (int gq = 0; gq < 2; ++gq) {
#pragma unroll
        for (int reg = 0; reg < 4; ++reg) {
            float linv = 1.f / ol[gq][reg];   // same C-layout row as o
            int row = qt * 128 + gq * 64 + wv * 16 + quad * 4 + reg;
            __bf16* op = O + ((size_t)(b * S) + row) * E + hh * 32;
            op[l15] = (__bf16)(o[gq][0][reg] * linv);
            op[16 + l15] = (__bf16)(o[gq][1][reg] * linv);
        }
    }
}

// ---------------- mega-fused: out-proj + res + LN1 + FFN1 + FFN2 + res + LN2 ----------------
__global__ __launch_bounds__(256) void k_layer2(const __bf16* __restrict__ t0b,
        const __bf16* __restrict__ Wo, const float* __restrict__ ob,
        const float* __restrict__ g1, const float* __restrict__ bt1,
        const __bf16* __restrict__ W1, const float* __restrict__ b1v,
        const __bf16* __restrict__ W2, const float* __restrict__ b2v,
        const float* __restrict__ g2, const float* __restrict__ bt2,
        __bf16* __restrict__ hb)
{
    __shared__ __attribute__((aligned(16))) __bf16 As[64][132];
    __shared__ __attribute__((aligned(16))) __bf16 Ws[128][132];
    __shared__ float red[2][64][2];
    int t = threadIdx.x;
    int m0 = blockIdx.x * 64;
    int arow = t >> 2, acol = (t & 3) * 32;
    int wrow = t >> 1, wcol = (t & 1) * 64;
    {
        const __bf16* Ap = t0b + (size_t)(m0 + arow) * 128 + acol;
#pragma unroll
        for (int j = 0; j < 4; ++j)
            st8(&As[arow][acol + j * 8], *(const bf16x8*)&Ap[j * 8]);
        const __bf16* Wp = Wo + (size_t)wrow * 128 + wcol;
#pragma unroll
        for (int j = 0; j < 8; ++j)
            st8(&Ws[wrow][wcol + j * 8], *(const bf16x8*)&Wp[j * 8]);
    }
    __syncthreads();
    int lane = t & 63, wv = t >> 6;
    int l15 = lane & 15, quad = lane >> 4;
    int nh = wv & 1, mh = wv >> 1;
    f32x4 acc[4][2];

    // ---------- phase A: out-proj ----------
#pragma unroll
    for (int i = 0; i < 4; ++i)
#pragma unroll
        for (int j = 0; j < 2; ++j) acc[i][j] = (f32x4){0.f, 0.f, 0.f, 0.f};
#pragma unroll
    for (int kc = 0; kc < 4; ++kc) {
        bf16x8 aw[4], ba[2];
#pragma unroll
        for (int nc = 0; nc < 4; ++nc)
            aw[nc] = ld8(&Ws[nh * 64 + nc * 16 + l15][kc * 32 + quad * 8]);
#pragma unroll
        for (int mc = 0; mc < 2; ++mc)
            ba[mc] = ld8(&As[mh * 32 + mc * 16 + l15][kc * 32 + quad * 8]);
#pragma unroll
        for (int nc = 0; nc < 4; ++nc)
#pragma unroll
            for (int mc = 0; mc < 2; ++mc)
                acc[nc][mc] = __builtin_amdgcn_mfma_f32_16x16x32_bf16(aw[nc], ba[mc], acc[nc][mc], 0, 0, 0);
    }
    float s1[2] = {0.f, 0.f}, s2[2] = {0.f, 0.f};
#pragma unroll
    for (int nc = 0; nc < 4; ++nc) {
        float4 bv = *(const float4*)&ob[nh * 64 + nc * 16 + quad * 4];
#pragma unroll
        for (int mc = 0; mc < 2; ++mc) {
            int m = m0 + mh * 32 + mc * 16 + l15;
            bf16x4 rv = *(const bf16x4*)&hb[(size_t)m * 128 + nh * 64 + nc * 16 + quad * 4];
            acc[nc][mc][0] += bv.x + (float)rv[0];
            acc[nc][mc][1] += bv.y + (float)rv[1];
            acc[nc][mc][2] += bv.z + (float)rv[2];
            acc[nc][mc][3] += bv.w + (float)rv[3];
#pragma unroll
            for (int i = 0; i < 4; ++i) {
                s1[mc] += acc[nc][mc][i];
                s2[mc] += acc[nc][mc][i] * acc[nc][mc][i];
            }
        }
    }
#pragma unroll
    for (int mc = 0; mc < 2; ++mc) {
        s1[mc] += __shfl_xor(s1[mc], 16); s1[mc] += __shfl_xor(s1[mc], 32);
        s2[mc] += __shfl_xor(s2[mc], 16); s2[mc] += __shfl_xor(s2[mc], 32);
    }
    if (quad == 0) {
#pragma unroll
        for (int mc = 0; mc < 2; ++mc) {
            red[nh][mh * 32 + mc * 16 + l15][0] = s1[mc];
            red[nh][mh * 32 + mc * 16 + l15][1] = s2[mc];
        }
    }
    __syncthreads();
    float mu[2], rs[2];
#pragma unroll
    for (int mc = 0; mc < 2; ++mc) {
        int r = mh * 32 + mc * 16 + l15;
        float S1 = red[0][r][0] + red[1][r][0];
        float S2 = red[0][r][1] + red[1][r][1];
        mu[mc] = S1 * (1.f / 128.f);
        float var = S2 * (1.f / 128.f) - mu[mc] * mu[mc];
        rs[mc] = rsqrtf(var + EPS);
    }
    bf16x4 res2[4][2];
#pragma unroll
    for (int nc = 0; nc < 4; ++nc) {
        float4 gv = *(const float4*)&g1[nh * 64 + nc * 16 + quad * 4];
        float4 bb = *(const float4*)&bt1[nh * 64 + nc * 16 + quad * 4];
#pragma unroll
        for (int mc = 0; mc < 2; ++mc) {
            float o0 = (acc[nc][mc][0] - mu[mc]) * rs[mc] * gv.x + bb.x;
            float o1 = (acc[nc][mc][1] - mu[mc]) * rs[mc] * gv.y + bb.y;
            float o2 = (acc[nc][mc][2] - mu[mc]) * rs[mc] * gv.z + bb.z;
            float o3 = (acc[nc][mc][3] - mu[mc]) * rs[mc] * gv.w + bb.w;
            bf16x4 xb;
            xb[0] = (__bf16)o0; xb[1] = (__bf16)o1;
            xb[2] = (__bf16)o2; xb[3] = (__bf16)o3;
            res2[nc][mc] = xb;
            *(bf16x4*)&As[mh * 32 + mc * 16 + l15][nh * 64 + nc * 16 + quad * 4] = xb;
        }
    }
    {
        const __bf16* Wp = W1 + (size_t)wrow * 128 + wcol;
#pragma unroll
        for (int j = 0; j < 8; ++j)
            st8(&Ws[wrow][wcol + j * 8], *(const bf16x8*)&Wp[j * 8]);
    }
    __syncthreads();

    // ---------- phase B: FFN1 ----------
#pragma unroll
    for (int i = 0; i < 4; ++i)
#pragma unroll
        for (int j = 0; j < 2; ++j) acc[i][j] = (f32x4){0.f, 0.f, 0.f, 0.f};
#pragma unroll
    for (int kc = 0; kc < 4; ++kc) {
        bf16x8 aw[4], ba[2];
#pragma unroll
        for (int nc = 0; nc < 4; ++nc)
            aw[nc] = ld8(&Ws[nh * 64 + nc * 16 + l15][kc * 32 + quad * 8]);
#pragma unroll
        for (int mc = 0; mc < 2; ++mc)
            ba[mc] = ld8(&As[mh * 32 + mc * 16 + l15][kc * 32 + quad * 8]);
#pragma unroll
        for (int nc = 0; nc < 4; ++nc)
#pragma unroll
            for (int mc = 0; mc < 2; ++mc)
                acc[nc][mc] = __builtin_amdgcn_mfma_f32_16x16x32_bf16(aw[nc], ba[mc], acc[nc][mc], 0, 0, 0);
    }
    __syncthreads();
#pragma unroll
    for (int nc = 0; nc < 4; ++nc) {
        float4 bv = *(const float4*)&b1v[nh * 64 + nc * 16 + quad * 4];
#pragma unroll
        for (int mc = 0; mc < 2; ++mc) {
            float v0 = fmaxf(acc[nc][mc][0] + bv.x, 0.f);
            float v1 = fmaxf(acc[nc][mc][1] + bv.y, 0.f);
            float v2 = fmaxf(acc[nc][mc][2] + bv.z, 0.f);
            float v3 = fmaxf(acc[nc][mc][3] + bv.w, 0.f);
            uint2 u; u.x = pk2(v0, v1); u.y = pk2(v2, v3);
            *(uint2*)&As[mh * 32 + mc * 16 + l15][nh * 64 + nc * 16 + quad * 4] = u;
        }
    }
    {
        const __bf16* Wp = W2 + (size_t)wrow * 128 + wcol;
#pragma unroll
        for (int j = 0; j < 8; ++j)
            st8(&Ws[wrow][wcol + j * 8], *(const bf16x8*)&Wp[j * 8]);
    }
    __syncthreads();

    // ---------- phase C: FFN2 + res2 + LN2 ----------
#pragma unroll
    for (int i = 0; i < 4; ++i)
#pragma unroll
        for (int j = 0; j < 2; ++j) acc[i][j] = (f32x4){0.f, 0.f, 0.f, 0.f};
#pragma unroll
    for (int kc = 0; kc < 4; ++kc) {
        bf16x8 aw[4], ba[2];
#pragma unroll
        for (int nc = 0; nc < 4; ++nc)
            aw[nc] = ld8(&Ws[nh * 64 + nc * 16 + l15][kc * 32 + quad * 8]);
#pragma unroll
        for (int mc = 0; mc < 2; ++mc)
            ba[mc] = ld8(&As[mh * 32 + mc * 16 + l15][kc * 32 + quad * 8]);
#pragma unroll
        for (int nc = 0; nc < 4; ++nc)
#pragma unroll
            for (int mc = 0; mc < 2; ++mc)
                acc[nc][mc] = __builtin_amdgcn_mfma_f32_16x16x32_bf16(aw[nc], ba[mc], acc[nc][mc], 0, 0, 0);
    }
    s1[0] = s1[1] = s2[0] = s2[1] = 0.f;
#pragma unroll
    for (int nc = 0; nc < 4; ++nc) {
        float4 bv = *(const float4*)&b2v[nh * 64 + nc * 16 + quad * 4];
#pragma unroll
        for (int mc = 0; mc < 2; ++mc) {
            acc[nc][mc][0] += bv.x + (float)res2[nc][mc][0];
            acc[nc][mc][1] += bv.y + (float)res2[nc][mc][1];
            acc[nc][mc][2] += bv.z + (float)res2[nc][mc][2];
            acc[nc][mc][3] += bv.w + (float)res2[nc][mc][3];
#pragma unroll
            for (int i = 0; i < 4; ++i) {
                s1[mc] += acc[nc][mc][i];
                s2[mc] += acc[nc][mc][i] * acc[nc][mc][i];
            }
        }
    }
#pragma unroll
    for (int mc = 0; mc < 2; ++mc) {
        s1[mc] += __shfl_xor(s1[mc], 16); s1[mc] += __shfl_xor(s1[mc], 32);
        s2[mc] += __shfl_xor(s2[mc], 16); s2[mc] += __shfl_xor(s2[mc], 32);
    }
    if (quad == 0) {
#pragma unroll
        for (int mc = 0; mc < 2; ++mc) {
            red[nh][mh * 32 + mc * 16 + l15][0] = s1[mc];
            red[nh][mh * 32 + mc * 16 + l15][1] = s2[mc];
        }
    }
    __syncthreads();
#pragma unroll
    for (int mc = 0; mc < 2; ++mc) {
        int r = mh * 32 + mc * 16 + l15;
        float S1 = red[0][r][0] + red[1][r][0];
        float S2 = red[0][r][1] + red[1][r][1];
        mu[mc] = S1 * (1.f / 128.f);
        float var = S2 * (1.f / 128.f) - mu[mc] * mu[mc];
        rs[mc] = rsqrtf(var + EPS);
    }
#pragma unroll
    for (int nc = 0; nc < 4; ++nc) {
        float4 gv = *(const float4*)&g2[nh * 64 + nc * 16 + quad * 4];
        float4 bb = *(const float4*)&bt2[nh * 64 + nc * 16 + quad * 4];
#pragma unroll
        for (int mc = 0; mc < 2; ++mc) {
            int m = m0 + mh * 32 + mc * 16 + l15;
            float o0 = (acc[nc][mc][0] - mu[mc]) * rs[mc] * gv.x + bb.x;
            float o1 = (acc[nc][mc][1] - mu[mc]) * rs[mc] * gv.y + bb.y;
            float o2 = (acc[nc][mc][2] - mu[mc]) * rs[mc] * gv.z + bb.z;
            float o3 = (acc[nc][mc][3] - mu[mc]) * rs[mc] * gv.w + bb.w;
            uint2 u; u.x = pk2(o0, o1); u.y = pk2(o2, o3);
            *(uint2*)&hb[(size_t)m * 128 + nh * 64 + nc * 16 + quad * 4] = u;
        }
    }
}

// ---------------- masked sum pool stage 1 (bf16 h) ----------------
__global__ __launch_bounds__(128) void k_pool1(const __bf16* __restrict__ h,
        const float* __restrict__ mask, float* __restrict__ part)
{
    int bx = blockIdx.x;
    int b = bx >> 3, ch = bx & 7, t = threadIdx.x;
    float acc = 0.f;
    const __bf16* hp = h + (size_t)(b * S + ch * 128) * E + t;
    const float* mp = mask + b * S + ch * 128;
    for (int s = 0; s < 128; ++s) acc += (float)hp[(size_t)s * E] * mp[s];
    part[(size_t)bx * E + t] = acc;
}

// ---------------- fused head: pool2 + cls1..3 + final sigmoid ----------------
__global__ __launch_bounds__(256) void k_head(const float* __restrict__ part,
        const float* __restrict__ cw1, const float* __restrict__ cb1,
        const float* __restrict__ cw2, const float* __restrict__ cb2,
        const float* __restrict__ cw3, const float* __restrict__ cb3,
        const float* __restrict__ cw4, const float* __restrict__ cb4,
        float* __restrict__ out)
{
    int b = blockIdx.x, t = threadIdx.x;
    __shared__ float p[128], za[256], zb[256];
    __shared__ float red4[4];
    if (t < 128) {
        float a = 0.f;
#pragma unroll
        for (int c = 0; c < 8; ++c) a += part[(size_t)(b * 8 + c) * 128 + t];
        p[t] = a;
    }
    __syncthreads();
    float a1 = cb1[t];
    for (int k = 0; k < 128; ++k) a1 += p[k] * cw1[t * 128 + k];
    za[t] = fmaxf(a1, 0.f);
    __syncthreads();
    float a2 = cb2[t];
    for (int k = 0; k < 256; ++k) a2 += za[k] * cw2[t * 256 + k];
    zb[t] = fmaxf(a2, 0.f);
    __syncthreads();
    float a3 = cb3[t];
    for (int k = 0; k < 256; ++k) a3 += zb[k] * cw3[t * 256 + k];
    float z3 = fmaxf(a3, 0.f);
    float prt = z3 * cw4[t];
#pragma unroll
    for (int o2 = 32; o2; o2 >>= 1) prt += __shfl_xor(prt, o2);
    if ((t & 63) == 0) red4[t >> 6] = prt;
    __syncthreads();
    if (t == 0) {
        float sum = red4[0] + red4[1] + red4[2] + red4[3] + cb4[0];
        out[b] = 1.f / (1.f + __expf(-sum));
    }
}

extern "C" void kernel_launch(void* const* d_in, const int* in_sizes, int n_in,
                              void* d_out, int out_size, void* d_ws, size_t ws_size,
                              hipStream_t stream)
{
    const float* x     = (const float*)d_in[0];
    const float* mask  = (const float*)d_in[1];
    const float* emb_w = (const float*)d_in[2];
    const float* emb_b = (const float*)d_in[3];
    const float* ipw   = (const float*)d_in[4];
    const float* ipb   = (const float*)d_in[5];
    const float* ow    = (const float*)d_in[6];
    const float* ob    = (const float*)d_in[7];
    const float* ln1g  = (const float*)d_in[8];
    const float* ln1b  = (const float*)d_in[9];
    const float* ln2g  = (const float*)d_in[10];
    const float* ln2b  = (const float*)d_in[11];
    const float* w1    = (const float*)d_in[12];
    const float* fb1   = (const float*)d_in[13];
    const float* w2    = (const float*)d_in[14];
    const float* fb2   = (const float*)d_in[15];
    const float* cw1   = (const float*)d_in[16];
    const float* cb1   = (const float*)d_in[17];
    const float* cw2   = (const float*)d_in[18];
    const float* cb2   = (const float*)d_in[19];
    const float* cw3   = (const float*)d_in[20];
    const float* cb3   = (const float*)d_in[21];
    const float* cw4   = (const float*)d_in[22];
    const float* cb4   = (const float*)d_in[23];

    char* p = (char*)d_ws;
    __bf16* hb   = (__bf16*)p;   p += (size_t)ROWS * E * 2;        // 8 MB bf16 stream
    __bf16* qkb  = (__bf16*)p;   p += (size_t)ROWS * 256 * 2;      // 16 MB Q|K rows
    __bf16* vtb  = (__bf16*)p;   p += (size_t)ROWS * 32 * 4 * 2 / 4; // 8 MB V^T [b,h,d,s]
    __bf16* t0b  = (__bf16*)p;   p += (size_t)ROWS * E * 2;        // 8 MB attn out
    __bf16* wb   = (__bf16*)p;   p += (size_t)(N_IPW + 3 * N_SQ) * 2;
    float* part  = (float*)p;    p += (size_t)B * 8 * E * 4;

    __bf16* wb_ipw = wb;
    __bf16* wb_ow  = wb + N_IPW;
    __bf16* wb_w1  = wb_ow + N_SQ;
    __bf16* wb_w2  = wb_w1 + N_SQ;

    k_embedcvt<<<NCVT + ROWS / 16, 256, 0, stream>>>(
        ipw, ow, w1, w2, wb, x, emb_w, emb_b, hb);
    for (int L = 0; L < 3; ++L) {
        k_gemm_qkv<<<dim3(6, ROWS / 128), 256, 0, stream>>>(
            hb, wb_ipw + (size_t)L * 384 * 128, ipb + L * 384, qkb, vtb);
        k_attn4<<<B * NH * (S / 128), 256, 0, stream>>>(qkb, vtb, t0b);
        k_layer2<<<ROWS / 64, 256, 0, stream>>>(
            t0b, wb_ow + (size_t)L * 128 * 128, ob + L * 128,
            ln1g + L * E, ln1b + L * E,
            wb_w1 + (size_t)L * 128 * 128, fb1 + L * 128,
            wb_w2 + (size_t)L * 128 * 128, fb2 + L * 128,
            ln2g + L * E, ln2b + L * E, hb);
    }
    k_pool1<<<B * 8, 128, 0, stream>>>(hb, mask, part);
    k_head<<<B, 256, 0, stream>>>(part, cw1, cb1, cw2, cb2, cw3, cb3, cw4, cb4,
                                  (float*)d_out);
}